// Round 13
// baseline (145.634 us; speedup 1.0000x reference)
//
#include <hip/hip_runtime.h>
#include <math.h>

#define NBATCH 32768
#define IND    784
#define KPAD1  800
#define HIDD   256
#define OUTD   1000
#define OUTDP  1024

typedef _Float16 half8  __attribute__((ext_vector_type(8)));
typedef _Float16 half4v __attribute__((ext_vector_type(4)));
typedef float    floatx4 __attribute__((ext_vector_type(4)));

#define GAS __attribute__((address_space(1)))
#define LAS __attribute__((address_space(3)))

#define WAITVM(N) asm volatile("s_waitcnt vmcnt(" #N ")" ::: "memory")
// counted-vmcnt + lgkmcnt(0) (raw s_barrier does NOT fence LDS ops) + barrier + sched pin
#define WAITVM_BAR(N)                                                      \
    asm volatile("s_waitcnt vmcnt(" #N ") lgkmcnt(0)" ::: "memory");       \
    __builtin_amdgcn_s_barrier();                                          \
    __builtin_amdgcn_sched_barrier(0)

__device__ __forceinline__ void gld16(const void* g, void* l) {
    __builtin_amdgcn_global_load_lds((const GAS void*)g, (LAS void*)l, 16, 0, 0);
}

__device__ __forceinline__ float wave_allreduce_sum(float v) {
    #pragma unroll
    for (int off = 32; off >= 1; off >>= 1) v += __shfl_xor(v, off);
    return v;
}

// ---------------- cvt_x: x fp32 [32768][784] -> x16 fp16 [32768][800] (zero-padded) ------------
// m13 copy pattern: flat granules, division-free (const div 100 -> magic mul), fully coalesced.
__global__ __launch_bounds__(256)
void cvt_x_kernel(const float* __restrict__ x, _Float16* __restrict__ x16)
{
    const unsigned NG = NBATCH * 100u;                 // dst granules (8 halves each)
    for (unsigned i = blockIdx.x * 256u + threadIdx.x; i < NG;
         i += (unsigned)gridDim.x * 256u) {
        const unsigned row = i / 100u;                 // magic-mul, cheap
        const unsigned g   = i - row * 100u;
        half8 o;
        if (g < 98u) {
            const float* s = &x[(size_t)row * IND + g * 8u];
            float4 v0 = *(const float4*)s, v1 = *(const float4*)(s + 4);
            o[0]=(_Float16)v0.x; o[1]=(_Float16)v0.y; o[2]=(_Float16)v0.z; o[3]=(_Float16)v0.w;
            o[4]=(_Float16)v1.x; o[5]=(_Float16)v1.y; o[6]=(_Float16)v1.z; o[7]=(_Float16)v1.w;
        } else {
            #pragma unroll
            for (int j = 0; j < 8; ++j) o[j] = (_Float16)0.0f;   // cols 784..799
        }
        *(half8*)&x16[(size_t)row * KPAD1 + g * 8u] = o;
    }
}

// ---------------- prep: w1 -> w1h (pad K to 800), w2 -> w2h (pad N to 1024), zero stats ----------
__global__ __launch_bounds__(256)
void prep_kernel(const float* __restrict__ w1, _Float16* __restrict__ w1h,
                 const float* __restrict__ w2, _Float16* __restrict__ w2h,
                 float* __restrict__ stat)
{
    const int tid = threadIdx.x;
    if (blockIdx.x == 0) {
        for (int j = tid; j < 1024 + 16; j += 256) stat[j] = 0.0f;   // sums/ssqs + zbuf
    }
    const int NW1 = HIDD * (KPAD1 / 8);     // 25600 granules
    const int NW2 = OUTDP * (HIDD / 8);     // 32768 granules
    for (int i = blockIdx.x * 256 + tid; i < NW1 + NW2; i += (int)gridDim.x * 256) {
        half8 o;
        if (i < NW1) {
            const int r = i / (KPAD1 / 8), c8 = (i % (KPAD1 / 8)) * 8;
            if (c8 + 8 <= IND) {
                const float* s = &w1[(size_t)r * IND + c8];
                float4 v0 = *(const float4*)s, v1 = *(const float4*)(s + 4);
                o[0]=(_Float16)v0.x; o[1]=(_Float16)v0.y; o[2]=(_Float16)v0.z; o[3]=(_Float16)v0.w;
                o[4]=(_Float16)v1.x; o[5]=(_Float16)v1.y; o[6]=(_Float16)v1.z; o[7]=(_Float16)v1.w;
            } else {
                #pragma unroll
                for (int j = 0; j < 8; ++j) o[j] = (_Float16)0.0f;
            }
            *(half8*)&w1h[(size_t)r * KPAD1 + c8] = o;
        } else {
            const int k = i - NW1;
            const int r = k >> 5, c8 = (k & 31) * 8;
            if (r < OUTD) {
                const float* s = &w2[(size_t)r * HIDD + c8];
                float4 v0 = *(const float4*)s, v1 = *(const float4*)(s + 4);
                o[0]=(_Float16)v0.x; o[1]=(_Float16)v0.y; o[2]=(_Float16)v0.z; o[3]=(_Float16)v0.w;
                o[4]=(_Float16)v1.x; o[5]=(_Float16)v1.y; o[6]=(_Float16)v1.z; o[7]=(_Float16)v1.w;
            } else {
                #pragma unroll
                for (int j = 0; j < 8; ++j) o[j] = (_Float16)0.0f;
            }
            *(half8*)&w2h[(size_t)r * HIDD + c8] = o;
        }
    }
}

// ================= GEMM1 v4: h = x16(fp16,K=800) @ w1h(fp16)^T + b1, BN1 stats =================
// Exact clone of the proven at-floor GEMM2 loop: depth-3 gld16 DMA, counted vmcnt(4),
// 128x128 tile, nbn=2, grid 512. x16 is L3-resident (written by cvt_x just before).
// No bounds checks (K padded to 800, N=256 full).
__global__ __launch_bounds__(256, 3)
void gemm1_kernel(const _Float16* __restrict__ x16, const _Float16* __restrict__ w1h,
                  const float* __restrict__ b1, const float* __restrict__ zbuf,
                  float* __restrict__ h, float* __restrict__ sum1, float* __restrict__ ssq1)
{
    __shared__ __align__(16) _Float16 ldsA[3][4096];   // 3 x 8KB
    __shared__ __align__(16) _Float16 ldsB[3][4096];
    __shared__ float redS[2][128], redQ[2][128];

    const int tid  = threadIdx.x;
    const int bid0 = blockIdx.x;
    const int vbid = (bid0 & 7) * 64 + (bid0 >> 3);    // XCD chunking (grid 512)
    const int bm = vbid >> 1, bn = vbid & 1;
    const int m0 = bm * 128, n0 = bn * 128;
    const int lane = tid & 63, wv = tid >> 6;
    const int wr = wv >> 1, wc = wv & 1;
    const int l15 = lane & 15, lg = lane >> 4;
    const int e3 = l15 & 3;
    const int nt = KPAD1 / 32;                          // 25

    const int srow = lane >> 2, sgp = (lane & 3) ^ (srow & 3);
    const _Float16* Ab = x16 + (size_t)(m0 + srow) * KPAD1 + sgp * 8;
    const _Float16* Bb = w1h + (size_t)(n0 + srow) * KPAD1 + sgp * 8;

    floatx4 acc[4][4];
    #pragma unroll
    for (int i = 0; i < 4; ++i)
        #pragma unroll
        for (int j = 0; j < 4; ++j) acc[i][j] = (floatx4){0.f, 0.f, 0.f, 0.f};

    auto STAGE = [&](int buf, int t) {                  // 4 gld16 per thread, always
        const int t32 = t * 32;
        const bool tok = t < nt;
        #pragma unroll
        for (int c = 0; c < 2; ++c) {
            const int ch = wv + c * 4;                  // chunks 0..7 (16 rows x 32k)
            const void* sa = tok ? (const void*)(Ab + (size_t)ch * 16 * KPAD1 + t32)
                                 : (const void*)zbuf;
            const void* sb = tok ? (const void*)(Bb + (size_t)ch * 16 * KPAD1 + t32)
                                 : (const void*)zbuf;
            gld16(sa, &ldsA[buf][ch * 512]);
            gld16(sb, &ldsB[buf][ch * 512]);
        }
    };

    STAGE(0, 0);
    STAGE(1, 1);
    WAITVM_BAR(4);

    int buf = 0;
    for (int t = 0; t < nt; ++t) {
        int nbuf = buf + 2; if (nbuf >= 3) nbuf -= 3;
        STAGE(nbuf, t + 2);
        half8 af[4], bfr[4];
        #pragma unroll
        for (int i = 0; i < 4; ++i)
            af[i] = *(const half8*)&ldsA[buf][(wr * 4 + i) * 512 + l15 * 32 + ((lg ^ e3) * 8)];
        #pragma unroll
        for (int j = 0; j < 4; ++j)
            bfr[j] = *(const half8*)&ldsB[buf][(wc * 4 + j) * 512 + l15 * 32 + ((lg ^ e3) * 8)];
        // swapped operands: lane holds m = l15, n = lg*4 + reg (coalesced stores)
        #pragma unroll
        for (int i = 0; i < 4; ++i)
            #pragma unroll
            for (int j = 0; j < 4; ++j)
                acc[i][j] = __builtin_amdgcn_mfma_f32_16x16x32_f16(bfr[j], af[i], acc[i][j], 0, 0, 0);
        WAITVM_BAR(4);
        buf = (buf + 1 == 3) ? 0 : buf + 1;
    }
    WAITVM(0);                                          // drain trailing zbuf loads

    // ---- epilogue: bias, float4 store, BN1 column stats ----
    float sJ[4][4], qJ[4][4];
    #pragma unroll
    for (int j = 0; j < 4; ++j)
        #pragma unroll
        for (int r = 0; r < 4; ++r) { sJ[j][r] = 0.f; qJ[j][r] = 0.f; }
    #pragma unroll
    for (int i = 0; i < 4; ++i) {
        const int m = m0 + wr * 64 + i * 16 + l15;
        #pragma unroll
        for (int j = 0; j < 4; ++j) {
            const int nb = n0 + wc * 64 + j * 16 + lg * 4;
            float4 bt = *reinterpret_cast<const float4*>(&b1[nb]);
            float v[4] = {acc[i][j][0] + bt.x, acc[i][j][1] + bt.y,
                          acc[i][j][2] + bt.z, acc[i][j][3] + bt.w};
            *reinterpret_cast<float4*>(&h[(size_t)m * HIDD + nb]) =
                make_float4(v[0], v[1], v[2], v[3]);
            #pragma unroll
            for (int r = 0; r < 4; ++r) { sJ[j][r] += v[r]; qJ[j][r] += v[r] * v[r]; }
        }
    }
    #pragma unroll
    for (int j = 0; j < 4; ++j)
        #pragma unroll
        for (int r = 0; r < 4; ++r) {
            float s = sJ[j][r], q = qJ[j][r];
            s += __shfl_xor(s, 1); s += __shfl_xor(s, 2);
            s += __shfl_xor(s, 4); s += __shfl_xor(s, 8);
            q += __shfl_xor(q, 1); q += __shfl_xor(q, 2);
            q += __shfl_xor(q, 4); q += __shfl_xor(q, 8);
            if (l15 == 0) {
                redS[wr][wc * 64 + j * 16 + lg * 4 + r] = s;
                redQ[wr][wc * 64 + j * 16 + lg * 4 + r] = q;
            }
        }
    __syncthreads();
    if (tid < 128) {
        atomicAdd(&sum1[n0 + tid], redS[0][tid] + redS[1][tid]);
        atomicAdd(&ssq1[n0 + tid], redQ[0][tid] + redQ[1][tid]);
    }
}

// ---------------- middle: BN1 finalize -> relu(bn1(h)) -> log_map0 -> butterfly x3 ->
//                  exp_map0 -> ht16 (x65536) + BN2 raw stats ----------------
__global__ __launch_bounds__(256)
void mid_kernel(const float* __restrict__ h, const float* __restrict__ bfp,
                const float* __restrict__ sum1, const float* __restrict__ ssq1,
                const float* __restrict__ g1, const float* __restrict__ be1,
                _Float16* __restrict__ ht16, float* __restrict__ sum2, float* __restrict__ ssq2)
{
    __shared__ float s1sh[256], t1sh[256];
    __shared__ float bsum[4][256], bssq[4][256];
    const int tid  = threadIdx.x;
    {
        const float inv = 1.0f / (float)NBATCH;
        const float mu  = sum1[tid] * inv;
        const float var = fmaxf(ssq1[tid] * inv - mu * mu, 0.0f);
        const float rs  = 1.0f / sqrtf(var + 1e-5f);
        const float sj  = g1[tid] * rs;
        s1sh[tid] = sj;
        t1sh[tid] = fmaf(-mu, sj, be1[tid]);
    }
    __syncthreads();

    const int w    = tid >> 6;
    const int lane = tid & 63;
    const int row0 = blockIdx.x * 64 + w * 16;
    const int c0   = lane * 4;

    const float4 s1v = *reinterpret_cast<const float4*>(&s1sh[c0]);
    const float4 t1v = *reinterpret_cast<const float4*>(&t1sh[c0]);
    const float a0 = bfp[2 * lane],       a1 = bfp[2 * lane + 1];
    const float b0 = bfp[128 + 2 * lane], b1 = bfp[128 + 2 * lane + 1];
    const float a2 = bfp[256 + lane],     b2 = bfp[320 + lane];
    const float a3 = bfp[384 + (lane >> 1)], b3 = bfp[416 + (lane >> 1)];
    const float sgn = (lane & 1) ? -1.0f : 1.0f;
    const float sc  = sqrtf(1e-3f);

    float ps0 = 0, ps1 = 0, ps2 = 0, ps3 = 0;
    float q0 = 0, q1 = 0, q2 = 0, q3 = 0;

    for (int r = 0; r < 16; ++r) {
        const int row = row0 + r;
        const float4 v = *reinterpret_cast<const float4*>(&h[(size_t)row * HIDD + c0]);
        float x0 = fmaxf(fmaf(v.x, s1v.x, t1v.x), 0.0f);
        float x1 = fmaxf(fmaf(v.y, s1v.y, t1v.y), 0.0f);
        float x2 = fmaxf(fmaf(v.z, s1v.z, t1v.z), 0.0f);
        float x3 = fmaxf(fmaf(v.w, s1v.w, t1v.w), 0.0f);
        float n2 = x0 * x0 + x1 * x1 + x2 * x2 + x3 * x3;
        n2 = wave_allreduce_sum(n2);
        float sn = sc * sqrtf(n2);
        sn = fminf(fmaxf(sn, 1e-7f), 1.0f - 1e-6f);
        const float ls = atanhf(sn) / sn;
        x0 *= ls; x1 *= ls; x2 *= ls; x3 *= ls;
        const float y0 = fmaf(a0, x0,  b0 * x1);
        const float y1 = fmaf(a0, x1, -b0 * x0);
        const float y2 = fmaf(a1, x2,  b1 * x3);
        const float y3 = fmaf(a1, x3, -b1 * x2);
        const float z0 = fmaf(a2, y0,  b2 * y2);
        const float z1 = fmaf(a2, y1,  b2 * y3);
        const float z2 = fmaf(a2, y2, -b2 * y0);
        const float z3 = fmaf(a2, y3, -b2 * y1);
        const float p0 = __shfl_xor(z0, 1);
        const float p1 = __shfl_xor(z1, 1);
        const float p2 = __shfl_xor(z2, 1);
        const float p3 = __shfl_xor(z3, 1);
        const float w0 = fmaf(a3, z0, sgn * (b3 * p0));
        const float w1 = fmaf(a3, z1, sgn * (b3 * p1));
        const float w2 = fmaf(a3, z2, sgn * (b3 * p2));
        const float w3 = fmaf(a3, z3, sgn * (b3 * p3));
        float m2 = w0 * w0 + w1 * w1 + w2 * w2 + w3 * w3;
        m2 = wave_allreduce_sum(m2);
        const float sn2 = fmaxf(sc * sqrtf(m2), 1e-7f);
        const float es = tanhf(sn2) / sn2;
        const float o0 = es * w0, o1 = es * w1, o2 = es * w2, o3 = es * w3;
        half4v hv;
        hv[0] = (_Float16)(o0 * 65536.0f); hv[1] = (_Float16)(o1 * 65536.0f);
        hv[2] = (_Float16)(o2 * 65536.0f); hv[3] = (_Float16)(o3 * 65536.0f);
        *reinterpret_cast<half4v*>(&ht16[(size_t)row * HIDD + c0]) = hv;
        ps0 += o0; ps1 += o1; ps2 += o2; ps3 += o3;
        q0 += o0 * o0; q1 += o1 * o1; q2 += o2 * o2; q3 += o3 * o3;
    }

    bsum[w][c0 + 0] = ps0; bsum[w][c0 + 1] = ps1; bsum[w][c0 + 2] = ps2; bsum[w][c0 + 3] = ps3;
    bssq[w][c0 + 0] = q0;  bssq[w][c0 + 1] = q1;  bssq[w][c0 + 2] = q2;  bssq[w][c0 + 3] = q3;
    __syncthreads();
    if (tid < 256) {
        const float s = bsum[0][tid] + bsum[1][tid] + bsum[2][tid] + bsum[3][tid];
        const float q = bssq[0][tid] + bssq[1][tid] + bssq[2][tid] + bssq[3][tid];
        atomicAdd(&sum2[tid], s);
        atomicAdd(&ssq2[tid], q);
    }
}

// ================= GEMM2: out = relu(bn2(ht)) @ w2h^T + b2, BN2 fused at fragment read =========
// Depth-3 DMA pipeline, counted vmcnt(4). A = ht16 (ht*65536); prologue finalizes BN2 into sf/tf.
__global__ __launch_bounds__(256, 3)
void gemm2_kernel(const _Float16* __restrict__ ht16, const _Float16* __restrict__ w2h,
                  const float* __restrict__ b2,
                  const float* __restrict__ sum2, const float* __restrict__ ssq2,
                  const float* __restrict__ g2, const float* __restrict__ be2,
                  const float* __restrict__ zbuf, float* __restrict__ out)
{
    __shared__ __align__(16) _Float16 ldsA[3][4096];   // 3 x 8KB
    __shared__ __align__(16) _Float16 ldsB[3][4096];
    __shared__ float sf[256], tf[256];

    const int tid = threadIdx.x;
    {
        const float inv = 1.0f / (float)NBATCH;
        const float mu  = sum2[tid] * inv;
        const float var = fmaxf(ssq2[tid] * inv - mu * mu, 0.0f);
        const float rs  = 1.0f / sqrtf(var + 1e-5f);
        const float sj  = g2[tid] * rs;
        sf[tid] = sj * (1024.0f / 65536.0f);
        tf[tid] = fmaf(-mu, sj, be2[tid]) * 1024.0f;
    }

    const int bid0 = blockIdx.x;
    const int vbid = (bid0 & 7) * 256 + (bid0 >> 3);   // XCD chunking (grid 2048)
    const int bm = vbid >> 3, bn = vbid & 7;
    const int m0 = bm * 128, n0 = bn * 128;
    const int lane = tid & 63, wv = tid >> 6;
    const int wr = wv >> 1, wc = wv & 1;
    const int l15 = lane & 15, lg = lane >> 4;
    const int e3 = l15 & 3;
    const int nt = HIDD / 32;                           // 8

    const int srow = lane >> 2, sgp = (lane & 3) ^ (srow & 3);
    const _Float16* Ab = ht16 + (size_t)(m0 + srow) * HIDD + sgp * 8;
    const _Float16* Bb = w2h  + (size_t)(n0 + srow) * HIDD + sgp * 8;

    floatx4 acc[4][4];
    #pragma unroll
    for (int i = 0; i < 4; ++i)
        #pragma unroll
        for (int j = 0; j < 4; ++j) acc[i][j] = (floatx4){0.f, 0.f, 0.f, 0.f};

    auto STAGE = [&](int buf, int t) {                  // 4 gld16 per thread, always
        const int t32 = t * 32;
        const bool tok = t < nt;
        #pragma unroll
        for (int c = 0; c < 2; ++c) {
            const int ch = wv + c * 4;                  // chunks 0..7 (16 rows x 32k)
            const void* sa = tok ? (const void*)(Ab + (size_t)ch * 16 * HIDD + t32)
                                 : (const void*)zbuf;
            const void* sb = tok ? (const void*)(Bb + (size_t)ch * 16 * HIDD + t32)
                                 : (const void*)zbuf;
            gld16(sa, &ldsA[buf][ch * 512]);
            gld16(sb, &ldsB[buf][ch * 512]);
        }
    };

    STAGE(0, 0);
    STAGE(1, 1);
    WAITVM_BAR(4);                                      // fences sf/tf (lgkmcnt(0)+barrier)

    int buf = 0;
    for (int t = 0; t < nt; ++t) {
        int nbuf = buf + 2; if (nbuf >= 3) nbuf -= 3;
        STAGE(nbuf, t + 2);
        const int kb = t * 32 + lg * 8;
        float4 s0 = *(const float4*)&sf[kb], s1 = *(const float4*)&sf[kb + 4];
        float4 t0 = *(const float4*)&tf[kb], t1 = *(const float4*)&tf[kb + 4];
        half8 af[4], bfr[4];
        #pragma unroll
        for (int i = 0; i < 4; ++i) {
            half8 v = *(const half8*)&ldsA[buf][(wr * 4 + i) * 512 + l15 * 32 + ((lg ^ e3) * 8)];
            half8 hv;
            hv[0] = (_Float16)fmaxf(fmaf((float)v[0], s0.x, t0.x), 0.0f);
            hv[1] = (_Float16)fmaxf(fmaf((float)v[1], s0.y, t0.y), 0.0f);
            hv[2] = (_Float16)fmaxf(fmaf((float)v[2], s0.z, t0.z), 0.0f);
            hv[3] = (_Float16)fmaxf(fmaf((float)v[3], s0.w, t0.w), 0.0f);
            hv[4] = (_Float16)fmaxf(fmaf((float)v[4], s1.x, t1.x), 0.0f);
            hv[5] = (_Float16)fmaxf(fmaf((float)v[5], s1.y, t1.y), 0.0f);
            hv[6] = (_Float16)fmaxf(fmaf((float)v[6], s1.z, t1.z), 0.0f);
            hv[7] = (_Float16)fmaxf(fmaf((float)v[7], s1.w, t1.w), 0.0f);
            af[i] = hv;
        }
        #pragma unroll
        for (int j = 0; j < 4; ++j)
            bfr[j] = *(const half8*)&ldsB[buf][(wc * 4 + j) * 512 + l15 * 32 + ((lg ^ e3) * 8)];
        #pragma unroll
        for (int i = 0; i < 4; ++i)
            #pragma unroll
            for (int j = 0; j < 4; ++j)
                acc[i][j] = __builtin_amdgcn_mfma_f32_16x16x32_f16(bfr[j], af[i], acc[i][j], 0, 0, 0);
        WAITVM_BAR(4);
        buf = (buf + 1 == 3) ? 0 : buf + 1;
    }
    WAITVM(0);                                          // drain trailing zbuf loads

    // epilogue: /1024, + bias, bounds-checked float4 store (N=1000 < padded 1024)
    const float invScale = 1.0f / 1024.0f;
    #pragma unroll
    for (int i = 0; i < 4; ++i) {
        const int m = m0 + wr * 64 + i * 16 + l15;
        #pragma unroll
        for (int j = 0; j < 4; ++j) {
            const int nb = n0 + wc * 64 + j * 16 + lg * 4;
            float bj[4];
            if (nb + 4 <= OUTD) {
                float4 bt = *reinterpret_cast<const float4*>(&b2[nb]);
                bj[0] = bt.x; bj[1] = bt.y; bj[2] = bt.z; bj[3] = bt.w;
            } else {
                #pragma unroll
                for (int r = 0; r < 4; ++r) bj[r] = (nb + r < OUTD) ? b2[nb + r] : 0.0f;
            }
            float v[4];
            #pragma unroll
            for (int r = 0; r < 4; ++r) v[r] = fmaf(acc[i][j][r], invScale, bj[r]);
            if (nb + 4 <= OUTD) {
                *reinterpret_cast<float4*>(&out[(size_t)m * OUTD + nb]) =
                    make_float4(v[0], v[1], v[2], v[3]);
            } else {
                #pragma unroll
                for (int r = 0; r < 4; ++r)
                    if (nb + r < OUTD) out[(size_t)m * OUTD + nb + r] = v[r];
            }
        }
    }
}

extern "C" void kernel_launch(void* const* d_in, const int* in_sizes, int n_in,
                              void* d_out, int out_size, void* d_ws, size_t ws_size,
                              hipStream_t stream)
{
    const float* x   = (const float*)d_in[0];
    const float* w1  = (const float*)d_in[1];
    const float* b1  = (const float*)d_in[2];
    const float* g1  = (const float*)d_in[3];
    const float* be1 = (const float*)d_in[4];
    const float* bfp = (const float*)d_in[5];
    const float* g2  = (const float*)d_in[6];
    const float* be2 = (const float*)d_in[7];
    const float* w2  = (const float*)d_in[8];
    const float* b2  = (const float*)d_in[9];

    float* out = (float*)d_out;
    char*  wsb = (char*)d_ws;

    // ws layout (all 16B aligned): ht16 | w1h | w2h | stats+zbuf   (~17.7 MB)
    _Float16* ht16 = (_Float16*)(wsb);                    // 32768 x 256 fp16
    _Float16* w1h  = (_Float16*)(wsb + 16777216);         //   256 x 800 fp16
    _Float16* w2h  = (_Float16*)(wsb + 17186816);         //  1024 x 256 fp16
    float*    stat = (float*)  (wsb + 17711104);          // 4 x 256 stats + 16 zbuf
    float* sum1 = stat;
    float* ssq1 = stat + 256;
    float* sum2 = stat + 512;
    float* ssq2 = stat + 768;
    float* zbuf = stat + 1024;

    // d_out parking: h fp32 [0 .. 8.39M floats); x16 fp16 at +8388608 floats (52.4 MB).
    // Both dead before GEMM2 overwrites the full 131 MB output.
    float*    h   = out;
    _Float16* x16 = (_Float16*)(out + 8388608);           // 32768 x 800 fp16

    // 1) streaming x conversion (division-free, coalesced — BW-bound)
    cvt_x_kernel<<<2048, 256, 0, stream>>>(x, x16);
    // 2) weight conversion + stats zeroing
    prep_kernel<<<232, 256, 0, stream>>>(w1, w1h, w2, w2h, stat);
    // 3) GEMM1 v4: pure-fp16 clone of the at-floor GEMM2 loop; x16 is L3-resident
    gemm1_kernel<<<512, 256, 0, stream>>>(x16, w1h, b1, zbuf, h, sum1, ssq1);
    // 4) BN1 finalize + relu + log-map + butterfly x3 + exp-map -> ht16, BN2 stats
    mid_kernel<<<512, 256, 0, stream>>>(h, bfp, sum1, ssq1, g1, be1, ht16, sum2, ssq2);
    // 5) GEMM2 with fused BN2+relu at fragment read
    gemm2_kernel<<<2048, 256, 0, stream>>>(ht16, w2h, b2, sum2, ssq2, g2, be2, zbuf, out);
}

// Round 14
// 127.161 us; speedup vs baseline: 1.1453x; 1.1453x over previous
//
#include <hip/hip_runtime.h>
#include <math.h>

#define NBATCH 32768
#define IND    784
#define KPAD1  800
#define HIDD   256
#define OUTD   1000
#define OUTDP  1024

typedef _Float16 half8  __attribute__((ext_vector_type(8)));
typedef _Float16 half4v __attribute__((ext_vector_type(4)));
typedef float    floatx4 __attribute__((ext_vector_type(4)));

#define GAS __attribute__((address_space(1)))
#define LAS __attribute__((address_space(3)))

#define WAITVM(N) asm volatile("s_waitcnt vmcnt(" #N ")" ::: "memory")
// counted-vmcnt + lgkmcnt(0) (raw s_barrier does NOT fence LDS ops) + barrier + sched pin
#define WAITVM_BAR(N)                                                      \
    asm volatile("s_waitcnt vmcnt(" #N ") lgkmcnt(0)" ::: "memory");       \
    __builtin_amdgcn_s_barrier();                                          \
    __builtin_amdgcn_sched_barrier(0)

__device__ __forceinline__ void gld16(const void* g, void* l) {
    __builtin_amdgcn_global_load_lds((const GAS void*)g, (LAS void*)l, 16, 0, 0);
}

__device__ __forceinline__ float wave_allreduce_sum(float v) {
    #pragma unroll
    for (int off = 32; off >= 1; off >>= 1) v += __shfl_xor(v, off);
    return v;
}

// ---------------- prep: w1 -> w1h (pad K to 800), w2 -> w2h (pad N to 1024), zero stats ----------
__global__ __launch_bounds__(256)
void prep_kernel(const float* __restrict__ w1, _Float16* __restrict__ w1h,
                 const float* __restrict__ w2, _Float16* __restrict__ w2h,
                 float* __restrict__ stat)
{
    const int tid = threadIdx.x;
    if (blockIdx.x == 0) {
        for (int j = tid; j < 1024 + 16; j += 256) stat[j] = 0.0f;   // sums/ssqs + zbuf
    }
    const int NW1 = HIDD * (KPAD1 / 8);     // 25600 granules
    const int NW2 = OUTDP * (HIDD / 8);     // 32768 granules
    for (int i = blockIdx.x * 256 + tid; i < NW1 + NW2; i += (int)gridDim.x * 256) {
        half8 o;
        if (i < NW1) {
            const int r = i / (KPAD1 / 8), c8 = (i % (KPAD1 / 8)) * 8;
            if (c8 + 8 <= IND) {
                const float* s = &w1[(size_t)r * IND + c8];
                float4 v0 = *(const float4*)s, v1 = *(const float4*)(s + 4);
                o[0]=(_Float16)v0.x; o[1]=(_Float16)v0.y; o[2]=(_Float16)v0.z; o[3]=(_Float16)v0.w;
                o[4]=(_Float16)v1.x; o[5]=(_Float16)v1.y; o[6]=(_Float16)v1.z; o[7]=(_Float16)v1.w;
            } else {
                #pragma unroll
                for (int j = 0; j < 8; ++j) o[j] = (_Float16)0.0f;
            }
            *(half8*)&w1h[(size_t)r * KPAD1 + c8] = o;
        } else {
            const int k = i - NW1;
            const int r = k >> 5, c8 = (k & 31) * 8;
            if (r < OUTD) {
                const float* s = &w2[(size_t)r * HIDD + c8];
                float4 v0 = *(const float4*)s, v1 = *(const float4*)(s + 4);
                o[0]=(_Float16)v0.x; o[1]=(_Float16)v0.y; o[2]=(_Float16)v0.z; o[3]=(_Float16)v0.w;
                o[4]=(_Float16)v1.x; o[5]=(_Float16)v1.y; o[6]=(_Float16)v1.z; o[7]=(_Float16)v1.w;
            } else {
                #pragma unroll
                for (int j = 0; j < 8; ++j) o[j] = (_Float16)0.0f;
            }
            *(half8*)&w2h[(size_t)r * HIDD + c8] = o;
        }
    }
}

// ================= GEMM1 (R9 config): h16 = fp16( x(fp32) @ w1h(fp16)^T + b1 ), BN1 stats ======
// A: REG-STAGED to fp16: 4x dwordx4 issued ~1.5 iters early -> cvt -> 2x ds_write_b128
//    just before the barrier. LDS A = fp16 [2][128][32] (+in-row XOR swizzle).
// B: gld16 DMA, fp16, 3 buffers. Single barrier/iter, counted vmcnt(6) (= 4 A-loads + 2 B-DMA).
// Epilogue stores h in FP16 (stats from pre-rounded fp32) — halves gemm1-write + mid-read traffic.
__global__ __launch_bounds__(256, 3)
void gemm1_kernel(const float* __restrict__ x, const _Float16* __restrict__ w1h,
                  const float* __restrict__ b1, const float* __restrict__ zbuf,
                  _Float16* __restrict__ h16, float* __restrict__ sum1, float* __restrict__ ssq1)
{
    __shared__ __align__(16) _Float16 ldsA[2][4096];   // 2 x 8KB
    __shared__ __align__(16) _Float16 ldsB[3][4096];   // 3 x 8KB
    __shared__ float redS[2][128], redQ[2][128];

    const int tid  = threadIdx.x;
    const int bid0 = blockIdx.x;
    const int vbid = (bid0 & 7) * 64 + (bid0 >> 3);    // XCD chunking (grid 512)
    const int bm = vbid >> 1, bn = vbid & 1;
    const int m0 = bm * 128, n0 = bn * 128;
    const int lane = tid & 63, wv = tid >> 6;
    const int wr = wv >> 1, wc = wv & 1;
    const int l15 = lane & 15, lg = lane >> 4;
    const int e3 = l15 & 3;
    const int nt = KPAD1 / 32;                          // 25

    // A reg-staging geometry: granule g = c*256+tid -> row g>>2, kq g&3 (8 k-floats)
    const int r0g = tid >> 2;            // rows 0..63   (c=0)
    const int r1g = 64 + (tid >> 2);     // rows 64..127 (c=1)
    const int kq  = tid & 3;
    const int wpos0 = r0g * 32 + ((kq ^ (r0g & 3)) * 8);   // swizzled LDS pos (halves)
    const int wpos1 = r1g * 32 + ((kq ^ (r1g & 3)) * 8);
    const float* Ab0 = x + (size_t)(m0 + r0g) * IND + kq * 8;
    const float* Ab1 = x + (size_t)(m0 + r1g) * IND + kq * 8;

    // B staging (DMA): granule=lane, row=lane>>2, source kq pre-swizzled
    const int brow = lane >> 2, bgp = (lane & 3) ^ (brow & 3);
    const _Float16* Bb = w1h + (size_t)(n0 + brow) * KPAD1 + bgp * 8;

    floatx4 acc[4][4];
    #pragma unroll
    for (int i = 0; i < 4; ++i)
        #pragma unroll
        for (int j = 0; j < 4; ++j) acc[i][j] = (floatx4){0.f, 0.f, 0.f, 0.f};

    floatx4 rgaE[4], rgaO[4];   // two named reg sets (even/odd tiles) — no runtime indexing

    auto A_ISSUE = [&](floatx4 (&rg)[4], int t) {       // 4 global_load_dwordx4
        const int t32 = t * 32;
        const bool v = (t32 + kq * 8) < IND;            // IND % 8 == 0
        const float* p0 = v ? (Ab0 + t32) : zbuf;
        const float* p1 = v ? (Ab1 + t32) : zbuf;
        rg[0] = *(const floatx4*)p0;
        rg[1] = *(const floatx4*)(p0 + 4);
        rg[2] = *(const floatx4*)p1;
        rg[3] = *(const floatx4*)(p1 + 4);
    };
    auto A_WRITE = [&](floatx4 (&rg)[4], int wb) {      // cvt + 2 ds_write_b128
        half8 h0, h1;
        #pragma unroll
        for (int j = 0; j < 4; ++j) {
            h0[j] = (_Float16)rg[0][j]; h0[4 + j] = (_Float16)rg[1][j];
            h1[j] = (_Float16)rg[2][j]; h1[4 + j] = (_Float16)rg[3][j];
        }
        *(half8*)&ldsA[wb][wpos0] = h0;
        *(half8*)&ldsA[wb][wpos1] = h1;
    };
    auto B_ISSUE = [&](int bb, int t) {                 // 2 gld16
        const int t32 = t * 32;
        const bool tok = t < nt;
        #pragma unroll
        for (int c = 0; c < 2; ++c) {
            const int ch = wv + c * 4;
            const void* s = tok ? (const void*)(Bb + (size_t)ch * 16 * KPAD1 + t32)
                                : (const void*)zbuf;
            gld16(s, &ldsB[bb][ch * 512]);
        }
    };

    auto COMPUTE = [&](int abuf, int brd) {
        half8 af[4], bfr[4];
        #pragma unroll
        for (int i = 0; i < 4; ++i)
            af[i] = *(const half8*)&ldsA[abuf][(wr * 64 + i * 16 + l15) * 32 + ((lg ^ e3) * 8)];
        #pragma unroll
        for (int j = 0; j < 4; ++j)
            bfr[j] = *(const half8*)&ldsB[brd][(wc * 4 + j) * 512 + l15 * 32 + ((lg ^ e3) * 8)];
        #pragma unroll
        for (int i = 0; i < 4; ++i)
            #pragma unroll
            for (int j = 0; j < 4; ++j)
                acc[i][j] = __builtin_amdgcn_mfma_f32_16x16x32_f16(bfr[j], af[i], acc[i][j], 0, 0, 0);
    };

    // ---- prologue: tile0 -> LDS (A via regs, B via DMA); tile1 in flight ----
    A_ISSUE(rgaE, 0); B_ISSUE(0, 0);
    WAITVM(2);                       // A(0) regs arrived
    A_WRITE(rgaE, 0);
    A_ISSUE(rgaO, 1); B_ISSUE(1, 1);
    WAITVM_BAR(6);                   // B(0) resident; A(0) ds_writes fenced; barrier

    // ---- main loop: 12 pairs (t=0..23), tile t in ldsA[t&1]/ldsB[t%3] ----
    int b0 = 0;
    for (int p = 0; p < 12; ++p) {
        const int t  = p * 2;
        const int b1v = b0 + 1 == 3 ? 0 : b0 + 1;
        const int b2v = b1v + 1 == 3 ? 0 : b1v + 1;
        // even iter: compute t (A buf0), issue t+2 -> rgaE/ldsB[b2], write A(t+1) from rgaO
        A_ISSUE(rgaE, t + 2);
        B_ISSUE(b2v, t + 2);
        COMPUTE(0, b0);
        __builtin_amdgcn_sched_barrier(0);
        WAITVM(6);
        A_WRITE(rgaO, 1);
        WAITVM_BAR(6);
        // odd iter: compute t+1 (A buf1), issue t+3 -> rgaO/ldsB[b0], write A(t+2) from rgaE
        A_ISSUE(rgaO, t + 3);
        B_ISSUE(b0, t + 3);
        COMPUTE(1, b1v);
        __builtin_amdgcn_sched_barrier(0);
        WAITVM(6);
        A_WRITE(rgaE, 0);
        WAITVM_BAR(6);
        b0 = b2v;
    }
    // ---- final iteration t=24 (tile resident; only zbuf loads outstanding) ----
    COMPUTE(0, b0);
    WAITVM(0);                       // drain trailing zbuf loads

    // ---- epilogue: bias, FP16 store (half4v), column stats from pre-rounded fp32 ----
    float sJ[4][4], qJ[4][4];
    #pragma unroll
    for (int j = 0; j < 4; ++j)
        #pragma unroll
        for (int r = 0; r < 4; ++r) { sJ[j][r] = 0.f; qJ[j][r] = 0.f; }
    #pragma unroll
    for (int i = 0; i < 4; ++i) {
        const int m = m0 + wr * 64 + i * 16 + l15;
        #pragma unroll
        for (int j = 0; j < 4; ++j) {
            const int nb = n0 + wc * 64 + j * 16 + lg * 4;
            float4 bt = *reinterpret_cast<const float4*>(&b1[nb]);
            float v[4] = {acc[i][j][0] + bt.x, acc[i][j][1] + bt.y,
                          acc[i][j][2] + bt.z, acc[i][j][3] + bt.w};
            half4v hv;
            hv[0] = (_Float16)v[0]; hv[1] = (_Float16)v[1];
            hv[2] = (_Float16)v[2]; hv[3] = (_Float16)v[3];
            *reinterpret_cast<half4v*>(&h16[(size_t)m * HIDD + nb]) = hv;
            #pragma unroll
            for (int r = 0; r < 4; ++r) { sJ[j][r] += v[r]; qJ[j][r] += v[r] * v[r]; }
        }
    }
    #pragma unroll
    for (int j = 0; j < 4; ++j)
        #pragma unroll
        for (int r = 0; r < 4; ++r) {
            float s = sJ[j][r], q = qJ[j][r];
            s += __shfl_xor(s, 1); s += __shfl_xor(s, 2);
            s += __shfl_xor(s, 4); s += __shfl_xor(s, 8);
            q += __shfl_xor(q, 1); q += __shfl_xor(q, 2);
            q += __shfl_xor(q, 4); q += __shfl_xor(q, 8);
            if (l15 == 0) {
                redS[wr][wc * 64 + j * 16 + lg * 4 + r] = s;
                redQ[wr][wc * 64 + j * 16 + lg * 4 + r] = q;
            }
        }
    __syncthreads();
    if (tid < 128) {
        atomicAdd(&sum1[n0 + tid], redS[0][tid] + redS[1][tid]);
        atomicAdd(&ssq1[n0 + tid], redQ[0][tid] + redQ[1][tid]);
    }
}

// ---------------- middle: BN1 finalize -> relu(bn1(h16)) -> log_map0 -> butterfly x3 ->
//                  exp_map0 -> ht16 (x65536) + BN2 raw stats ----------------
__global__ __launch_bounds__(256)
void mid_kernel(const _Float16* __restrict__ h16, const float* __restrict__ bfp,
                const float* __restrict__ sum1, const float* __restrict__ ssq1,
                const float* __restrict__ g1, const float* __restrict__ be1,
                _Float16* __restrict__ ht16, float* __restrict__ sum2, float* __restrict__ ssq2)
{
    __shared__ float s1sh[256], t1sh[256];
    __shared__ float bsum[4][256], bssq[4][256];
    const int tid  = threadIdx.x;
    {
        const float inv = 1.0f / (float)NBATCH;
        const float mu  = sum1[tid] * inv;
        const float var = fmaxf(ssq1[tid] * inv - mu * mu, 0.0f);
        const float rs  = 1.0f / sqrtf(var + 1e-5f);
        const float sj  = g1[tid] * rs;
        s1sh[tid] = sj;
        t1sh[tid] = fmaf(-mu, sj, be1[tid]);
    }
    __syncthreads();

    const int w    = tid >> 6;
    const int lane = tid & 63;
    const int row0 = blockIdx.x * 64 + w * 16;
    const int c0   = lane * 4;

    const float4 s1v = *reinterpret_cast<const float4*>(&s1sh[c0]);
    const float4 t1v = *reinterpret_cast<const float4*>(&t1sh[c0]);
    const float a0 = bfp[2 * lane],       a1 = bfp[2 * lane + 1];
    const float b0 = bfp[128 + 2 * lane], b1 = bfp[128 + 2 * lane + 1];
    const float a2 = bfp[256 + lane],     b2 = bfp[320 + lane];
    const float a3 = bfp[384 + (lane >> 1)], b3 = bfp[416 + (lane >> 1)];
    const float sgn = (lane & 1) ? -1.0f : 1.0f;
    const float sc  = sqrtf(1e-3f);

    float ps0 = 0, ps1 = 0, ps2 = 0, ps3 = 0;
    float q0 = 0, q1 = 0, q2 = 0, q3 = 0;

    for (int r = 0; r < 16; ++r) {
        const int row = row0 + r;
        half4v hv4 = *reinterpret_cast<const half4v*>(&h16[(size_t)row * HIDD + c0]);
        float x0 = fmaxf(fmaf((float)hv4[0], s1v.x, t1v.x), 0.0f);
        float x1 = fmaxf(fmaf((float)hv4[1], s1v.y, t1v.y), 0.0f);
        float x2 = fmaxf(fmaf((float)hv4[2], s1v.z, t1v.z), 0.0f);
        float x3 = fmaxf(fmaf((float)hv4[3], s1v.w, t1v.w), 0.0f);
        float n2 = x0 * x0 + x1 * x1 + x2 * x2 + x3 * x3;
        n2 = wave_allreduce_sum(n2);
        float sn = sc * sqrtf(n2);
        sn = fminf(fmaxf(sn, 1e-7f), 1.0f - 1e-6f);
        const float ls = atanhf(sn) / sn;
        x0 *= ls; x1 *= ls; x2 *= ls; x3 *= ls;
        const float y0 = fmaf(a0, x0,  b0 * x1);
        const float y1 = fmaf(a0, x1, -b0 * x0);
        const float y2 = fmaf(a1, x2,  b1 * x3);
        const float y3 = fmaf(a1, x3, -b1 * x2);
        const float z0 = fmaf(a2, y0,  b2 * y2);
        const float z1 = fmaf(a2, y1,  b2 * y3);
        const float z2 = fmaf(a2, y2, -b2 * y0);
        const float z3 = fmaf(a2, y3, -b2 * y1);
        const float p0 = __shfl_xor(z0, 1);
        const float p1 = __shfl_xor(z1, 1);
        const float p2 = __shfl_xor(z2, 1);
        const float p3 = __shfl_xor(z3, 1);
        const float w0 = fmaf(a3, z0, sgn * (b3 * p0));
        const float w1 = fmaf(a3, z1, sgn * (b3 * p1));
        const float w2 = fmaf(a3, z2, sgn * (b3 * p2));
        const float w3 = fmaf(a3, z3, sgn * (b3 * p3));
        float m2 = w0 * w0 + w1 * w1 + w2 * w2 + w3 * w3;
        m2 = wave_allreduce_sum(m2);
        const float sn2 = fmaxf(sc * sqrtf(m2), 1e-7f);
        const float es = tanhf(sn2) / sn2;
        const float o0 = es * w0, o1 = es * w1, o2 = es * w2, o3 = es * w3;
        half4v hv;
        hv[0] = (_Float16)(o0 * 65536.0f); hv[1] = (_Float16)(o1 * 65536.0f);
        hv[2] = (_Float16)(o2 * 65536.0f); hv[3] = (_Float16)(o3 * 65536.0f);
        *reinterpret_cast<half4v*>(&ht16[(size_t)row * HIDD + c0]) = hv;
        ps0 += o0; ps1 += o1; ps2 += o2; ps3 += o3;
        q0 += o0 * o0; q1 += o1 * o1; q2 += o2 * o2; q3 += o3 * o3;
    }

    bsum[w][c0 + 0] = ps0; bsum[w][c0 + 1] = ps1; bsum[w][c0 + 2] = ps2; bsum[w][c0 + 3] = ps3;
    bssq[w][c0 + 0] = q0;  bssq[w][c0 + 1] = q1;  bssq[w][c0 + 2] = q2;  bssq[w][c0 + 3] = q3;
    __syncthreads();
    if (tid < 256) {
        const float s = bsum[0][tid] + bsum[1][tid] + bsum[2][tid] + bsum[3][tid];
        const float q = bssq[0][tid] + bssq[1][tid] + bssq[2][tid] + bssq[3][tid];
        atomicAdd(&sum2[tid], s);
        atomicAdd(&ssq2[tid], q);
    }
}

// ================= GEMM2: out = relu(bn2(ht)) @ w2h^T + b2, BN2 fused at fragment read =========
// Depth-3 DMA pipeline, counted vmcnt(4). A = ht16 (ht*65536); prologue finalizes BN2 into sf/tf.
__global__ __launch_bounds__(256, 3)
void gemm2_kernel(const _Float16* __restrict__ ht16, const _Float16* __restrict__ w2h,
                  const float* __restrict__ b2,
                  const float* __restrict__ sum2, const float* __restrict__ ssq2,
                  const float* __restrict__ g2, const float* __restrict__ be2,
                  const float* __restrict__ zbuf, float* __restrict__ out)
{
    __shared__ __align__(16) _Float16 ldsA[3][4096];   // 3 x 8KB
    __shared__ __align__(16) _Float16 ldsB[3][4096];
    __shared__ float sf[256], tf[256];

    const int tid = threadIdx.x;
    {
        const float inv = 1.0f / (float)NBATCH;
        const float mu  = sum2[tid] * inv;
        const float var = fmaxf(ssq2[tid] * inv - mu * mu, 0.0f);
        const float rs  = 1.0f / sqrtf(var + 1e-5f);
        const float sj  = g2[tid] * rs;
        sf[tid] = sj * (1024.0f / 65536.0f);
        tf[tid] = fmaf(-mu, sj, be2[tid]) * 1024.0f;
    }

    const int bid0 = blockIdx.x;
    const int vbid = (bid0 & 7) * 256 + (bid0 >> 3);   // XCD chunking (grid 2048)
    const int bm = vbid >> 3, bn = vbid & 7;
    const int m0 = bm * 128, n0 = bn * 128;
    const int lane = tid & 63, wv = tid >> 6;
    const int wr = wv >> 1, wc = wv & 1;
    const int l15 = lane & 15, lg = lane >> 4;
    const int e3 = l15 & 3;
    const int nt = HIDD / 32;                           // 8

    const int srow = lane >> 2, sgp = (lane & 3) ^ (srow & 3);
    const _Float16* Ab = ht16 + (size_t)(m0 + srow) * HIDD + sgp * 8;
    const _Float16* Bb = w2h  + (size_t)(n0 + srow) * HIDD + sgp * 8;

    floatx4 acc[4][4];
    #pragma unroll
    for (int i = 0; i < 4; ++i)
        #pragma unroll
        for (int j = 0; j < 4; ++j) acc[i][j] = (floatx4){0.f, 0.f, 0.f, 0.f};

    auto STAGE = [&](int buf, int t) {                  // 4 gld16 per thread, always
        const int t32 = t * 32;
        const bool tok = t < nt;
        #pragma unroll
        for (int c = 0; c < 2; ++c) {
            const int ch = wv + c * 4;                  // chunks 0..7 (16 rows x 32k)
            const void* sa = tok ? (const void*)(Ab + (size_t)ch * 16 * HIDD + t32)
                                 : (const void*)zbuf;
            const void* sb = tok ? (const void*)(Bb + (size_t)ch * 16 * HIDD + t32)
                                 : (const void*)zbuf;
            gld16(sa, &ldsA[buf][ch * 512]);
            gld16(sb, &ldsB[buf][ch * 512]);
        }
    };

    STAGE(0, 0);
    STAGE(1, 1);
    WAITVM_BAR(4);                                      // fences sf/tf (lgkmcnt(0)+barrier)

    int buf = 0;
    for (int t = 0; t < nt; ++t) {
        int nbuf = buf + 2; if (nbuf >= 3) nbuf -= 3;
        STAGE(nbuf, t + 2);
        const int kb = t * 32 + lg * 8;
        float4 s0 = *(const float4*)&sf[kb], s1 = *(const float4*)&sf[kb + 4];
        float4 t0 = *(const float4*)&tf[kb], t1 = *(const float4*)&tf[kb + 4];
        half8 af[4], bfr[4];
        #pragma unroll
        for (int i = 0; i < 4; ++i) {
            half8 v = *(const half8*)&ldsA[buf][(wr * 4 + i) * 512 + l15 * 32 + ((lg ^ e3) * 8)];
            half8 hv;
            hv[0] = (_Float16)fmaxf(fmaf((float)v[0], s0.x, t0.x), 0.0f);
            hv[1] = (_Float16)fmaxf(fmaf((float)v[1], s0.y, t0.y), 0.0f);
            hv[2] = (_Float16)fmaxf(fmaf((float)v[2], s0.z, t0.z), 0.0f);
            hv[3] = (_Float16)fmaxf(fmaf((float)v[3], s0.w, t0.w), 0.0f);
            hv[4] = (_Float16)fmaxf(fmaf((float)v[4], s1.x, t1.x), 0.0f);
            hv[5] = (_Float16)fmaxf(fmaf((float)v[5], s1.y, t1.y), 0.0f);
            hv[6] = (_Float16)fmaxf(fmaf((float)v[6], s1.z, t1.z), 0.0f);
            hv[7] = (_Float16)fmaxf(fmaf((float)v[7], s1.w, t1.w), 0.0f);
            af[i] = hv;
        }
        #pragma unroll
        for (int j = 0; j < 4; ++j)
            bfr[j] = *(const half8*)&ldsB[buf][(wc * 4 + j) * 512 + l15 * 32 + ((lg ^ e3) * 8)];
        #pragma unroll
        for (int i = 0; i < 4; ++i)
            #pragma unroll
            for (int j = 0; j < 4; ++j)
                acc[i][j] = __builtin_amdgcn_mfma_f32_16x16x32_f16(bfr[j], af[i], acc[i][j], 0, 0, 0);
        WAITVM_BAR(4);
        buf = (buf + 1 == 3) ? 0 : buf + 1;
    }
    WAITVM(0);                                          // drain trailing zbuf loads

    // epilogue: /1024, + bias, bounds-checked float4 store (N=1000 < padded 1024)
    const float invScale = 1.0f / 1024.0f;
    #pragma unroll
    for (int i = 0; i < 4; ++i) {
        const int m = m0 + wr * 64 + i * 16 + l15;
        #pragma unroll
        for (int j = 0; j < 4; ++j) {
            const int nb = n0 + wc * 64 + j * 16 + lg * 4;
            float bj[4];
            if (nb + 4 <= OUTD) {
                float4 bt = *reinterpret_cast<const float4*>(&b2[nb]);
                bj[0] = bt.x; bj[1] = bt.y; bj[2] = bt.z; bj[3] = bt.w;
            } else {
                #pragma unroll
                for (int r = 0; r < 4; ++r) bj[r] = (nb + r < OUTD) ? b2[nb + r] : 0.0f;
            }
            float v[4];
            #pragma unroll
            for (int r = 0; r < 4; ++r) v[r] = fmaf(acc[i][j][r], invScale, bj[r]);
            if (nb + 4 <= OUTD) {
                *reinterpret_cast<float4*>(&out[(size_t)m * OUTD + nb]) =
                    make_float4(v[0], v[1], v[2], v[3]);
            } else {
                #pragma unroll
                for (int r = 0; r < 4; ++r)
                    if (nb + r < OUTD) out[(size_t)m * OUTD + nb + r] = v[r];
            }
        }
    }
}

extern "C" void kernel_launch(void* const* d_in, const int* in_sizes, int n_in,
                              void* d_out, int out_size, void* d_ws, size_t ws_size,
                              hipStream_t stream)
{
    const float* x   = (const float*)d_in[0];
    const float* w1  = (const float*)d_in[1];
    const float* b1  = (const float*)d_in[2];
    const float* g1  = (const float*)d_in[3];
    const float* be1 = (const float*)d_in[4];
    const float* bfp = (const float*)d_in[5];
    const float* g2  = (const float*)d_in[6];
    const float* be2 = (const float*)d_in[7];
    const float* w2  = (const float*)d_in[8];
    const float* b2  = (const float*)d_in[9];

    float* out = (float*)d_out;
    char*  wsb = (char*)d_ws;

    // ws layout (all 16B aligned): ht16 | w1h | w2h | stats+zbuf   (~17.7 MB)
    _Float16* ht16 = (_Float16*)(wsb);                    // 32768 x 256 fp16
    _Float16* w1h  = (_Float16*)(wsb + 16777216);         //   256 x 800 fp16
    _Float16* w2h  = (_Float16*)(wsb + 17186816);         //  1024 x 256 fp16
    float*    stat = (float*)  (wsb + 17711104);          // 4 x 256 stats + 16 zbuf
    float* sum1 = stat;
    float* ssq1 = stat + 256;
    float* sum2 = stat + 512;
    float* ssq2 = stat + 768;
    float* zbuf = stat + 1024;

    // park h16 [32768][256] fp16 in d_out; consumed by mid before GEMM2 overwrites
    _Float16* h16 = (_Float16*)out;

    // 1) weight conversion + stats zeroing
    prep_kernel<<<232, 256, 0, stream>>>(w1, w1h, w2, w2h, stat);
    // 2) GEMM1 (R9 config: reg-staged fp16 A, counted-vmcnt pipeline) + BN1 stats, h16 out
    gemm1_kernel<<<512, 256, 0, stream>>>(x, w1h, b1, zbuf, h16, sum1, ssq1);
    // 3) BN1 finalize + relu + log-map + butterfly x3 + exp-map -> ht16, BN2 stats
    mid_kernel<<<512, 256, 0, stream>>>(h16, bfp, sum1, ssq1, g1, be1, ht16, sum2, ssq2);
    // 4) GEMM2 with fused BN2+relu at fragment read (depth-3 counted-vmcnt pipeline)
    gemm2_kernel<<<2048, 256, 0, stream>>>(ht16, w2h, b2, sum2, ssq2, g2, be2, zbuf, out);
}

// Round 15
// 126.935 us; speedup vs baseline: 1.1473x; 1.0018x over previous
//
#include <hip/hip_runtime.h>
#include <math.h>

#define NBATCH 32768
#define IND    784
#define KPAD1  832          // 13 x 64
#define HIDD   256
#define OUTD   1000
#define OUTDP  1024

typedef _Float16 half8  __attribute__((ext_vector_type(8)));
typedef _Float16 half4v __attribute__((ext_vector_type(4)));
typedef float    floatx4 __attribute__((ext_vector_type(4)));

#define GAS __attribute__((address_space(1)))
#define LAS __attribute__((address_space(3)))

#define WAITVM(N) asm volatile("s_waitcnt vmcnt(" #N ")" ::: "memory")
// counted-vmcnt + lgkmcnt(0) (raw s_barrier does NOT fence LDS ops) + barrier + sched pin
#define WAITVM_BAR(N)                                                      \
    asm volatile("s_waitcnt vmcnt(" #N ") lgkmcnt(0)" ::: "memory");       \
    __builtin_amdgcn_s_barrier();                                          \
    __builtin_amdgcn_sched_barrier(0)

__device__ __forceinline__ void gld16(const void* g, void* l) {
    __builtin_amdgcn_global_load_lds((const GAS void*)g, (LAS void*)l, 16, 0, 0);
}

__device__ __forceinline__ float wave_allreduce_sum(float v) {
    #pragma unroll
    for (int off = 32; off >= 1; off >>= 1) v += __shfl_xor(v, off);
    return v;
}

// ---------------- prep: w1 -> w1h (pad K to 832), w2 -> w2h (pad N to 1024), zero stats ----------
__global__ __launch_bounds__(256)
void prep_kernel(const float* __restrict__ w1, _Float16* __restrict__ w1h,
                 const float* __restrict__ w2, _Float16* __restrict__ w2h,
                 float* __restrict__ stat)
{
    const int tid = threadIdx.x;
    if (blockIdx.x == 0) {
        for (int j = tid; j < 1024 + 16; j += 256) stat[j] = 0.0f;   // sums/ssqs + zbuf
    }
    const int NW1 = HIDD * (KPAD1 / 8);     // 256*104 granules
    const int NW2 = OUTDP * (HIDD / 8);     // 32768 granules
    for (int i = blockIdx.x * 256 + tid; i < NW1 + NW2; i += (int)gridDim.x * 256) {
        half8 o;
        if (i < NW1) {
            const int r = i / (KPAD1 / 8), c8 = (i % (KPAD1 / 8)) * 8;
            if (c8 + 8 <= IND) {
                const float* s = &w1[(size_t)r * IND + c8];
                float4 v0 = *(const float4*)s, v1 = *(const float4*)(s + 4);
                o[0]=(_Float16)v0.x; o[1]=(_Float16)v0.y; o[2]=(_Float16)v0.z; o[3]=(_Float16)v0.w;
                o[4]=(_Float16)v1.x; o[5]=(_Float16)v1.y; o[6]=(_Float16)v1.z; o[7]=(_Float16)v1.w;
            } else {
                #pragma unroll
                for (int j = 0; j < 8; ++j) o[j] = (_Float16)0.0f;
            }
            *(half8*)&w1h[(size_t)r * KPAD1 + c8] = o;
        } else {
            const int k = i - NW1;
            const int r = k >> 5, c8 = (k & 31) * 8;
            if (r < OUTD) {
                const float* s = &w2[(size_t)r * HIDD + c8];
                float4 v0 = *(const float4*)s, v1 = *(const float4*)(s + 4);
                o[0]=(_Float16)v0.x; o[1]=(_Float16)v0.y; o[2]=(_Float16)v0.z; o[3]=(_Float16)v0.w;
                o[4]=(_Float16)v1.x; o[5]=(_Float16)v1.y; o[6]=(_Float16)v1.z; o[7]=(_Float16)v1.w;
            } else {
                #pragma unroll
                for (int j = 0; j < 8; ++j) o[j] = (_Float16)0.0f;
            }
            *(half8*)&w2h[(size_t)r * HIDD + c8] = o;
        }
    }
}

// ================= GEMM1 (BK=64): h16 = fp16( x(fp32) @ w1h(fp16)^T + b1 ), BN1 stats =========
// 13 barrier-iterations (was 25): each K-step = TWO of R9's proven 32-k subtiles.
// A: reg-staged (8 dwordx4/iter, named E/O sets) -> cvt -> 4 ds_write_b128.  B: gld16 DMA.
// Issue order per iter: B(t+1) BEFORE A(t+2) so vmcnt(8) retires exactly {A(t+1),B(t+1)}
// (vmcnt retires in issue order). LDS 64KB -> 2 blocks/CU = grid 512 exactly resident.
__global__ __launch_bounds__(256, 2)
void gemm1_kernel(const float* __restrict__ x, const _Float16* __restrict__ w1h,
                  const float* __restrict__ b1, const float* __restrict__ zbuf,
                  _Float16* __restrict__ h16, float* __restrict__ sum1, float* __restrict__ ssq1)
{
    __shared__ __align__(16) _Float16 ldsA[2][8192];   // [buf][ks*4096 + row*32 + swz]
    __shared__ __align__(16) _Float16 ldsB[2][8192];   // [buf][ks*4096 + ch*512 + lane*8]
    __shared__ float redS[2][128], redQ[2][128];

    const int tid  = threadIdx.x;
    const int bid0 = blockIdx.x;
    const int vbid = (bid0 & 7) * 64 + (bid0 >> 3);    // XCD chunking (grid 512)
    const int bm = vbid >> 1, bn = vbid & 1;
    const int m0 = bm * 128, n0 = bn * 128;
    const int lane = tid & 63, wv = tid >> 6;
    const int wr = wv >> 1, wc = wv & 1;
    const int l15 = lane & 15, lg = lane >> 4;
    const int e3 = l15 & 3;
    const int nt = KPAD1 / 64;                          // 13

    // A reg-staging: rows tid>>2 and 64+(tid>>2), granule kq = tid&3 (8 floats), per ks
    const int r0g = tid >> 2, r1g = 64 + (tid >> 2), kq = tid & 3;
    const int wpos0 = r0g * 32 + ((kq ^ (r0g & 3)) * 8);
    const int wpos1 = r1g * 32 + ((kq ^ (r1g & 3)) * 8);
    const float* Ab0 = x + (size_t)(m0 + r0g) * IND + kq * 8;
    const float* Ab1 = x + (size_t)(m0 + r1g) * IND + kq * 8;

    // B staging (DMA): per ks, chunk = 16 rows x 32k (1KB); wave stages chunks wv, wv+4
    const int brow = lane >> 2, bgp = (lane & 3) ^ (brow & 3);
    const _Float16* Bb = w1h + (size_t)(n0 + brow) * KPAD1 + bgp * 8;

    floatx4 acc[4][4];
    #pragma unroll
    for (int i = 0; i < 4; ++i)
        #pragma unroll
        for (int j = 0; j < 4; ++j) acc[i][j] = (floatx4){0.f, 0.f, 0.f, 0.f};

    floatx4 rgaE[8], rgaO[8];   // named reg sets (even/odd tiles) — static indexing only

    auto A_ISSUE = [&](floatx4 (&rg)[8], int t) {       // 8 global_load_dwordx4
        #pragma unroll
        for (int ks = 0; ks < 2; ++ks) {
            const int off = t * 64 + ks * 32;
            const bool v = (off + kq * 8) < IND;        // IND % 8 == 0, granule-exact
            const float* p0 = v ? (Ab0 + off) : zbuf;
            const float* p1 = v ? (Ab1 + off) : zbuf;
            rg[ks*4+0] = *(const floatx4*)p0;
            rg[ks*4+1] = *(const floatx4*)(p0 + 4);
            rg[ks*4+2] = *(const floatx4*)p1;
            rg[ks*4+3] = *(const floatx4*)(p1 + 4);
        }
    };
    auto A_WRITE = [&](floatx4 (&rg)[8], int wb) {      // cvt + 4 ds_write_b128
        #pragma unroll
        for (int ks = 0; ks < 2; ++ks) {
            half8 h0, h1;
            #pragma unroll
            for (int j = 0; j < 4; ++j) {
                h0[j] = (_Float16)rg[ks*4+0][j]; h0[4+j] = (_Float16)rg[ks*4+1][j];
                h1[j] = (_Float16)rg[ks*4+2][j]; h1[4+j] = (_Float16)rg[ks*4+3][j];
            }
            *(half8*)&ldsA[wb][ks * 4096 + wpos0] = h0;
            *(half8*)&ldsA[wb][ks * 4096 + wpos1] = h1;
        }
    };
    auto B_ISSUE = [&](int bb, int t) {                 // 4 gld16
        const bool tok = t < nt;
        #pragma unroll
        for (int ks = 0; ks < 2; ++ks)
            #pragma unroll
            for (int c = 0; c < 2; ++c) {
                const int ch = wv + c * 4;
                const void* s = tok ? (const void*)(Bb + (size_t)ch * 16 * KPAD1 + t * 64 + ks * 32)
                                    : (const void*)zbuf;
                gld16(s, &ldsB[bb][ks * 4096 + ch * 512]);
            }
    };
    auto COMPUTE = [&](int abuf, int brd) {             // 2 ks-slices x 16 MFMA
        #pragma unroll
        for (int ks = 0; ks < 2; ++ks) {
            half8 af[4], bfr[4];
            #pragma unroll
            for (int i = 0; i < 4; ++i)
                af[i] = *(const half8*)&ldsA[abuf][ks*4096 + (wr*64 + i*16 + l15)*32 + ((lg ^ e3)*8)];
            #pragma unroll
            for (int j = 0; j < 4; ++j)
                bfr[j] = *(const half8*)&ldsB[brd][ks*4096 + (wc*4 + j)*512 + l15*32 + ((lg ^ e3)*8)];
            #pragma unroll
            for (int i = 0; i < 4; ++i)
                #pragma unroll
                for (int j = 0; j < 4; ++j)
                    acc[i][j] = __builtin_amdgcn_mfma_f32_16x16x32_f16(bfr[j], af[i], acc[i][j], 0, 0, 0);
        }
    };

    // ---- prologue: tile0 -> LDS (A regs + B DMA); A(1) in flight ----
    A_ISSUE(rgaE, 0);                // 8
    B_ISSUE(0, 0);                   // +4 = 12
    WAITVM(4);                       // retire A(0) regs (oldest 8)
    A_WRITE(rgaE, 0);
    A_ISSUE(rgaO, 1);                // +8 = 12
    WAITVM_BAR(8);                   // retire B(0); A(1) stays; A(0) ds_writes fenced

    // ---- main loop: 6 pairs (tiles 0..11); tile t: A buf t&1, B buf t&1 ----
    for (int p = 0; p < 6; ++p) {
        const int t = p * 2;
        // even: compute t; B(t+1) BEFORE A(t+2) (vmcnt issue-order discipline)
        B_ISSUE(1, t + 1);
        A_ISSUE(rgaE, t + 2);
        COMPUTE(0, 0);
        __builtin_amdgcn_sched_barrier(0);
        WAITVM(8);                   // retires A(t+1)[8] + B(t+1)[4]; A(t+2) in flight
        A_WRITE(rgaO, 1);
        WAITVM_BAR(8);
        // odd: compute t+1
        B_ISSUE(0, t + 2);
        A_ISSUE(rgaO, t + 3);
        COMPUTE(1, 1);
        __builtin_amdgcn_sched_barrier(0);
        WAITVM(8);                   // retires A(t+2)[8] + B(t+2)[4]
        A_WRITE(rgaE, 0);
        WAITVM_BAR(8);
    }
    // ---- final tile t=12 (A buf0 written in last odd; B(12) in buf0) ----
    COMPUTE(0, 0);
    WAITVM(0);                       // drain trailing zbuf loads

    // ---- epilogue: bias, FP16 store, column stats from pre-rounded fp32 ----
    float sJ[4][4], qJ[4][4];
    #pragma unroll
    for (int j = 0; j < 4; ++j)
        #pragma unroll
        for (int r = 0; r < 4; ++r) { sJ[j][r] = 0.f; qJ[j][r] = 0.f; }
    #pragma unroll
    for (int i = 0; i < 4; ++i) {
        const int m = m0 + wr * 64 + i * 16 + l15;
        #pragma unroll
        for (int j = 0; j < 4; ++j) {
            const int nb = n0 + wc * 64 + j * 16 + lg * 4;
            float4 bt = *reinterpret_cast<const float4*>(&b1[nb]);
            float v[4] = {acc[i][j][0] + bt.x, acc[i][j][1] + bt.y,
                          acc[i][j][2] + bt.z, acc[i][j][3] + bt.w};
            half4v hv;
            hv[0] = (_Float16)v[0]; hv[1] = (_Float16)v[1];
            hv[2] = (_Float16)v[2]; hv[3] = (_Float16)v[3];
            *reinterpret_cast<half4v*>(&h16[(size_t)m * HIDD + nb]) = hv;
            #pragma unroll
            for (int r = 0; r < 4; ++r) { sJ[j][r] += v[r]; qJ[j][r] += v[r] * v[r]; }
        }
    }
    #pragma unroll
    for (int j = 0; j < 4; ++j)
        #pragma unroll
        for (int r = 0; r < 4; ++r) {
            float s = sJ[j][r], q = qJ[j][r];
            s += __shfl_xor(s, 1); s += __shfl_xor(s, 2);
            s += __shfl_xor(s, 4); s += __shfl_xor(s, 8);
            q += __shfl_xor(q, 1); q += __shfl_xor(q, 2);
            q += __shfl_xor(q, 4); q += __shfl_xor(q, 8);
            if (l15 == 0) {
                redS[wr][wc * 64 + j * 16 + lg * 4 + r] = s;
                redQ[wr][wc * 64 + j * 16 + lg * 4 + r] = q;
            }
        }
    __syncthreads();
    if (tid < 128) {
        atomicAdd(&sum1[n0 + tid], redS[0][tid] + redS[1][tid]);
        atomicAdd(&ssq1[n0 + tid], redQ[0][tid] + redQ[1][tid]);
    }
}

// ---------------- middle: BN1 finalize -> relu(bn1(h16)) -> log_map0 -> butterfly x3 ->
//                  exp_map0 -> ht16 (x65536) + BN2 raw stats ----------------
__global__ __launch_bounds__(256)
void mid_kernel(const _Float16* __restrict__ h16, const float* __restrict__ bfp,
                const float* __restrict__ sum1, const float* __restrict__ ssq1,
                const float* __restrict__ g1, const float* __restrict__ be1,
                _Float16* __restrict__ ht16, float* __restrict__ sum2, float* __restrict__ ssq2)
{
    __shared__ float s1sh[256], t1sh[256];
    __shared__ float bsum[4][256], bssq[4][256];
    const int tid  = threadIdx.x;
    {
        const float inv = 1.0f / (float)NBATCH;
        const float mu  = sum1[tid] * inv;
        const float var = fmaxf(ssq1[tid] * inv - mu * mu, 0.0f);
        const float rs  = 1.0f / sqrtf(var + 1e-5f);
        const float sj  = g1[tid] * rs;
        s1sh[tid] = sj;
        t1sh[tid] = fmaf(-mu, sj, be1[tid]);
    }
    __syncthreads();

    const int w    = tid >> 6;
    const int lane = tid & 63;
    const int row0 = blockIdx.x * 64 + w * 16;
    const int c0   = lane * 4;

    const float4 s1v = *reinterpret_cast<const float4*>(&s1sh[c0]);
    const float4 t1v = *reinterpret_cast<const float4*>(&t1sh[c0]);
    const float a0 = bfp[2 * lane],       a1 = bfp[2 * lane + 1];
    const float b0 = bfp[128 + 2 * lane], b1 = bfp[128 + 2 * lane + 1];
    const float a2 = bfp[256 + lane],     b2 = bfp[320 + lane];
    const float a3 = bfp[384 + (lane >> 1)], b3 = bfp[416 + (lane >> 1)];
    const float sgn = (lane & 1) ? -1.0f : 1.0f;
    const float sc  = sqrtf(1e-3f);

    float ps0 = 0, ps1 = 0, ps2 = 0, ps3 = 0;
    float q0 = 0, q1 = 0, q2 = 0, q3 = 0;

    for (int r = 0; r < 16; ++r) {
        const int row = row0 + r;
        half4v hv4 = *reinterpret_cast<const half4v*>(&h16[(size_t)row * HIDD + c0]);
        float x0 = fmaxf(fmaf((float)hv4[0], s1v.x, t1v.x), 0.0f);
        float x1 = fmaxf(fmaf((float)hv4[1], s1v.y, t1v.y), 0.0f);
        float x2 = fmaxf(fmaf((float)hv4[2], s1v.z, t1v.z), 0.0f);
        float x3 = fmaxf(fmaf((float)hv4[3], s1v.w, t1v.w), 0.0f);
        float n2 = x0 * x0 + x1 * x1 + x2 * x2 + x3 * x3;
        n2 = wave_allreduce_sum(n2);
        float sn = sc * sqrtf(n2);
        sn = fminf(fmaxf(sn, 1e-7f), 1.0f - 1e-6f);
        const float ls = atanhf(sn) / sn;
        x0 *= ls; x1 *= ls; x2 *= ls; x3 *= ls;
        const float y0 = fmaf(a0, x0,  b0 * x1);
        const float y1 = fmaf(a0, x1, -b0 * x0);
        const float y2 = fmaf(a1, x2,  b1 * x3);
        const float y3 = fmaf(a1, x3, -b1 * x2);
        const float z0 = fmaf(a2, y0,  b2 * y2);
        const float z1 = fmaf(a2, y1,  b2 * y3);
        const float z2 = fmaf(a2, y2, -b2 * y0);
        const float z3 = fmaf(a2, y3, -b2 * y1);
        const float p0 = __shfl_xor(z0, 1);
        const float p1 = __shfl_xor(z1, 1);
        const float p2 = __shfl_xor(z2, 1);
        const float p3 = __shfl_xor(z3, 1);
        const float w0 = fmaf(a3, z0, sgn * (b3 * p0));
        const float w1 = fmaf(a3, z1, sgn * (b3 * p1));
        const float w2 = fmaf(a3, z2, sgn * (b3 * p2));
        const float w3 = fmaf(a3, z3, sgn * (b3 * p3));
        float m2 = w0 * w0 + w1 * w1 + w2 * w2 + w3 * w3;
        m2 = wave_allreduce_sum(m2);
        const float sn2 = fmaxf(sc * sqrtf(m2), 1e-7f);
        const float es = tanhf(sn2) / sn2;
        const float o0 = es * w0, o1 = es * w1, o2 = es * w2, o3 = es * w3;
        half4v hv;
        hv[0] = (_Float16)(o0 * 65536.0f); hv[1] = (_Float16)(o1 * 65536.0f);
        hv[2] = (_Float16)(o2 * 65536.0f); hv[3] = (_Float16)(o3 * 65536.0f);
        *reinterpret_cast<half4v*>(&ht16[(size_t)row * HIDD + c0]) = hv;
        ps0 += o0; ps1 += o1; ps2 += o2; ps3 += o3;
        q0 += o0 * o0; q1 += o1 * o1; q2 += o2 * o2; q3 += o3 * o3;
    }

    bsum[w][c0 + 0] = ps0; bsum[w][c0 + 1] = ps1; bsum[w][c0 + 2] = ps2; bsum[w][c0 + 3] = ps3;
    bssq[w][c0 + 0] = q0;  bssq[w][c0 + 1] = q1;  bssq[w][c0 + 2] = q2;  bssq[w][c0 + 3] = q3;
    __syncthreads();
    if (tid < 256) {
        const float s = bsum[0][tid] + bsum[1][tid] + bsum[2][tid] + bsum[3][tid];
        const float q = bssq[0][tid] + bssq[1][tid] + bssq[2][tid] + bssq[3][tid];
        atomicAdd(&sum2[tid], s);
        atomicAdd(&ssq2[tid], q);
    }
}

// ================= GEMM2: out = relu(bn2(ht)) @ w2h^T + b2, BN2 fused at fragment read =========
// Depth-3 DMA pipeline, counted vmcnt(4). A = ht16 (ht*65536); prologue finalizes BN2 into sf/tf.
__global__ __launch_bounds__(256, 3)
void gemm2_kernel(const _Float16* __restrict__ ht16, const _Float16* __restrict__ w2h,
                  const float* __restrict__ b2,
                  const float* __restrict__ sum2, const float* __restrict__ ssq2,
                  const float* __restrict__ g2, const float* __restrict__ be2,
                  const float* __restrict__ zbuf, float* __restrict__ out)
{
    __shared__ __align__(16) _Float16 ldsA[3][4096];   // 3 x 8KB
    __shared__ __align__(16) _Float16 ldsB[3][4096];
    __shared__ float sf[256], tf[256];

    const int tid = threadIdx.x;
    {
        const float inv = 1.0f / (float)NBATCH;
        const float mu  = sum2[tid] * inv;
        const float var = fmaxf(ssq2[tid] * inv - mu * mu, 0.0f);
        const float rs  = 1.0f / sqrtf(var + 1e-5f);
        const float sj  = g2[tid] * rs;
        sf[tid] = sj * (1024.0f / 65536.0f);
        tf[tid] = fmaf(-mu, sj, be2[tid]) * 1024.0f;
    }

    const int bid0 = blockIdx.x;
    const int vbid = (bid0 & 7) * 256 + (bid0 >> 3);   // XCD chunking (grid 2048)
    const int bm = vbid >> 3, bn = vbid & 7;
    const int m0 = bm * 128, n0 = bn * 128;
    const int lane = tid & 63, wv = tid >> 6;
    const int wr = wv >> 1, wc = wv & 1;
    const int l15 = lane & 15, lg = lane >> 4;
    const int e3 = l15 & 3;
    const int nt = HIDD / 32;                           // 8

    const int srow = lane >> 2, sgp = (lane & 3) ^ (srow & 3);
    const _Float16* Ab = ht16 + (size_t)(m0 + srow) * HIDD + sgp * 8;
    const _Float16* Bb = w2h  + (size_t)(n0 + srow) * HIDD + sgp * 8;

    floatx4 acc[4][4];
    #pragma unroll
    for (int i = 0; i < 4; ++i)
        #pragma unroll
        for (int j = 0; j < 4; ++j) acc[i][j] = (floatx4){0.f, 0.f, 0.f, 0.f};

    auto STAGE = [&](int buf, int t) {                  // 4 gld16 per thread, always
        const int t32 = t * 32;
        const bool tok = t < nt;
        #pragma unroll
        for (int c = 0; c < 2; ++c) {
            const int ch = wv + c * 4;                  // chunks 0..7 (16 rows x 32k)
            const void* sa = tok ? (const void*)(Ab + (size_t)ch * 16 * HIDD + t32)
                                 : (const void*)zbuf;
            const void* sb = tok ? (const void*)(Bb + (size_t)ch * 16 * HIDD + t32)
                                 : (const void*)zbuf;
            gld16(sa, &ldsA[buf][ch * 512]);
            gld16(sb, &ldsB[buf][ch * 512]);
        }
    };

    STAGE(0, 0);
    STAGE(1, 1);
    WAITVM_BAR(4);                                      // fences sf/tf (lgkmcnt(0)+barrier)

    int buf = 0;
    for (int t = 0; t < nt; ++t) {
        int nbuf = buf + 2; if (nbuf >= 3) nbuf -= 3;
        STAGE(nbuf, t + 2);
        const int kb = t * 32 + lg * 8;
        float4 s0 = *(const float4*)&sf[kb], s1 = *(const float4*)&sf[kb + 4];
        float4 t0 = *(const float4*)&tf[kb], t1 = *(const float4*)&tf[kb + 4];
        half8 af[4], bfr[4];
        #pragma unroll
        for (int i = 0; i < 4; ++i) {
            half8 v = *(const half8*)&ldsA[buf][(wr * 4 + i) * 512 + l15 * 32 + ((lg ^ e3) * 8)];
            half8 hv;
            hv[0] = (_Float16)fmaxf(fmaf((float)v[0], s0.x, t0.x), 0.0f);
            hv[1] = (_Float16)fmaxf(fmaf((float)v[1], s0.y, t0.y), 0.0f);
            hv[2] = (_Float16)fmaxf(fmaf((float)v[2], s0.z, t0.z), 0.0f);
            hv[3] = (_Float16)fmaxf(fmaf((float)v[3], s0.w, t0.w), 0.0f);
            hv[4] = (_Float16)fmaxf(fmaf((float)v[4], s1.x, t1.x), 0.0f);
            hv[5] = (_Float16)fmaxf(fmaf((float)v[5], s1.y, t1.y), 0.0f);
            hv[6] = (_Float16)fmaxf(fmaf((float)v[6], s1.z, t1.z), 0.0f);
            hv[7] = (_Float16)fmaxf(fmaf((float)v[7], s1.w, t1.w), 0.0f);
            af[i] = hv;
        }
        #pragma unroll
        for (int j = 0; j < 4; ++j)
            bfr[j] = *(const half8*)&ldsB[buf][(wc * 4 + j) * 512 + l15 * 32 + ((lg ^ e3) * 8)];
        #pragma unroll
        for (int i = 0; i < 4; ++i)
            #pragma unroll
            for (int j = 0; j < 4; ++j)
                acc[i][j] = __builtin_amdgcn_mfma_f32_16x16x32_f16(bfr[j], af[i], acc[i][j], 0, 0, 0);
        WAITVM_BAR(4);
        buf = (buf + 1 == 3) ? 0 : buf + 1;
    }
    WAITVM(0);                                          // drain trailing zbuf loads

    // epilogue: /1024, + bias, bounds-checked float4 store (N=1000 < padded 1024)
    const float invScale = 1.0f / 1024.0f;
    #pragma unroll
    for (int i = 0; i < 4; ++i) {
        const int m = m0 + wr * 64 + i * 16 + l15;
        #pragma unroll
        for (int j = 0; j < 4; ++j) {
            const int nb = n0 + wc * 64 + j * 16 + lg * 4;
            float bj[4];
            if (nb + 4 <= OUTD) {
                float4 bt = *reinterpret_cast<const float4*>(&b2[nb]);
                bj[0] = bt.x; bj[1] = bt.y; bj[2] = bt.z; bj[3] = bt.w;
            } else {
                #pragma unroll
                for (int r = 0; r < 4; ++r) bj[r] = (nb + r < OUTD) ? b2[nb + r] : 0.0f;
            }
            float v[4];
            #pragma unroll
            for (int r = 0; r < 4; ++r) v[r] = fmaf(acc[i][j][r], invScale, bj[r]);
            if (nb + 4 <= OUTD) {
                *reinterpret_cast<float4*>(&out[(size_t)m * OUTD + nb]) =
                    make_float4(v[0], v[1], v[2], v[3]);
            } else {
                #pragma unroll
                for (int r = 0; r < 4; ++r)
                    if (nb + r < OUTD) out[(size_t)m * OUTD + nb + r] = v[r];
            }
        }
    }
}

extern "C" void kernel_launch(void* const* d_in, const int* in_sizes, int n_in,
                              void* d_out, int out_size, void* d_ws, size_t ws_size,
                              hipStream_t stream)
{
    const float* x   = (const float*)d_in[0];
    const float* w1  = (const float*)d_in[1];
    const float* b1  = (const float*)d_in[2];
    const float* g1  = (const float*)d_in[3];
    const float* be1 = (const float*)d_in[4];
    const float* bfp = (const float*)d_in[5];
    const float* g2  = (const float*)d_in[6];
    const float* be2 = (const float*)d_in[7];
    const float* w2  = (const float*)d_in[8];
    const float* b2  = (const float*)d_in[9];

    float* out = (float*)d_out;
    char*  wsb = (char*)d_ws;

    // ws layout (all 16B aligned): ht16 | w1h | w2h | stats+zbuf   (~17.8 MB)
    _Float16* ht16 = (_Float16*)(wsb);                    // 32768 x 256 fp16
    _Float16* w1h  = (_Float16*)(wsb + 16777216);         //   256 x 832 fp16 (426KB)
    _Float16* w2h  = (_Float16*)(wsb + 17203200);         //  1024 x 256 fp16
    float*    stat = (float*)  (wsb + 17727488);          // 4 x 256 stats + 16 zbuf
    float* sum1 = stat;
    float* ssq1 = stat + 256;
    float* sum2 = stat + 512;
    float* ssq2 = stat + 768;
    float* zbuf = stat + 1024;

    // park h16 [32768][256] fp16 in d_out; consumed by mid before GEMM2 overwrites
    _Float16* h16 = (_Float16*)out;

    // 1) weight conversion + stats zeroing
    prep_kernel<<<232, 256, 0, stream>>>(w1, w1h, w2, w2h, stat);
    // 2) GEMM1 BK=64 (13 barrier-iters, reg-staged A + DMA B) + BN1 stats, h16 out
    gemm1_kernel<<<512, 256, 0, stream>>>(x, w1h, b1, zbuf, h16, sum1, ssq1);
    // 3) BN1 finalize + relu + log-map + butterfly x3 + exp-map -> ht16, BN2 stats
    mid_kernel<<<512, 256, 0, stream>>>(h16, bfp, sum1, ssq1, g1, be1, ht16, sum2, ssq2);
    // 4) GEMM2 with fused BN2+relu at fragment read (depth-3 counted-vmcnt pipeline)
    gemm2_kernel<<<2048, 256, 0, stream>>>(ht16, w2h, b2, sum2, ssq2, g2, be2, zbuf, out);
}

// Round 16
// 125.198 us; speedup vs baseline: 1.1632x; 1.0139x over previous
//
#include <hip/hip_runtime.h>
#include <math.h>

#define NBATCH 32768
#define IND    784
#define KPAD1  832          // 13 x 64
#define HIDD   256
#define OUTD   1000
#define OUTDP  1024

typedef _Float16 half8  __attribute__((ext_vector_type(8)));
typedef _Float16 half4v __attribute__((ext_vector_type(4)));
typedef float    floatx4 __attribute__((ext_vector_type(4)));

#define GAS __attribute__((address_space(1)))
#define LAS __attribute__((address_space(3)))

#define WAITVM(N) asm volatile("s_waitcnt vmcnt(" #N ")" ::: "memory")
// counted-vmcnt + lgkmcnt(0) (raw s_barrier does NOT fence LDS ops) + barrier + sched pin
#define WAITVM_BAR(N)                                                      \
    asm volatile("s_waitcnt vmcnt(" #N ") lgkmcnt(0)" ::: "memory");       \
    __builtin_amdgcn_s_barrier();                                          \
    __builtin_amdgcn_sched_barrier(0)

__device__ __forceinline__ void gld16(const void* g, void* l) {
    __builtin_amdgcn_global_load_lds((const GAS void*)g, (LAS void*)l, 16, 0, 0);
}

__device__ __forceinline__ float wave_allreduce_sum(float v) {
    #pragma unroll
    for (int off = 32; off >= 1; off >>= 1) v += __shfl_xor(v, off);
    return v;
}

// fast transcendentals on pre-clamped domains (single v_log_f32 / v_exp_f32):
// atanh(s), s in [1e-7, 1-1e-6]:  0.5*log((1+s)/(1-s))
__device__ __forceinline__ float fast_atanh(float s) {
    return 0.5f * __logf((1.0f + s) * __frcp_rn(1.0f - s));
}
// tanh(x), x >= 1e-7:  (1-e^-2x)/(1+e^-2x)
__device__ __forceinline__ float fast_tanh(float x) {
    const float e = __expf(-2.0f * x);
    return (1.0f - e) * __frcp_rn(1.0f + e);
}

// ---------------- prep: w1 -> w1h (pad K to 832), w2 -> w2h (pad N to 1024), zero stats ----------
__global__ __launch_bounds__(256)
void prep_kernel(const float* __restrict__ w1, _Float16* __restrict__ w1h,
                 const float* __restrict__ w2, _Float16* __restrict__ w2h,
                 float* __restrict__ stat)
{
    const int tid = threadIdx.x;
    if (blockIdx.x == 0) {
        for (int j = tid; j < 1024 + 16; j += 256) stat[j] = 0.0f;   // sums/ssqs + zbuf
    }
    const int NW1 = HIDD * (KPAD1 / 8);     // 256*104 granules
    const int NW2 = OUTDP * (HIDD / 8);     // 32768 granules
    for (int i = blockIdx.x * 256 + tid; i < NW1 + NW2; i += (int)gridDim.x * 256) {
        half8 o;
        if (i < NW1) {
            const int r = i / (KPAD1 / 8), c8 = (i % (KPAD1 / 8)) * 8;
            if (c8 + 8 <= IND) {
                const float* s = &w1[(size_t)r * IND + c8];
                float4 v0 = *(const float4*)s, v1 = *(const float4*)(s + 4);
                o[0]=(_Float16)v0.x; o[1]=(_Float16)v0.y; o[2]=(_Float16)v0.z; o[3]=(_Float16)v0.w;
                o[4]=(_Float16)v1.x; o[5]=(_Float16)v1.y; o[6]=(_Float16)v1.z; o[7]=(_Float16)v1.w;
            } else {
                #pragma unroll
                for (int j = 0; j < 8; ++j) o[j] = (_Float16)0.0f;
            }
            *(half8*)&w1h[(size_t)r * KPAD1 + c8] = o;
        } else {
            const int k = i - NW1;
            const int r = k >> 5, c8 = (k & 31) * 8;
            if (r < OUTD) {
                const float* s = &w2[(size_t)r * HIDD + c8];
                float4 v0 = *(const float4*)s, v1 = *(const float4*)(s + 4);
                o[0]=(_Float16)v0.x; o[1]=(_Float16)v0.y; o[2]=(_Float16)v0.z; o[3]=(_Float16)v0.w;
                o[4]=(_Float16)v1.x; o[5]=(_Float16)v1.y; o[6]=(_Float16)v1.z; o[7]=(_Float16)v1.w;
            } else {
                #pragma unroll
                for (int j = 0; j < 8; ++j) o[j] = (_Float16)0.0f;
            }
            *(half8*)&w2h[(size_t)r * HIDD + c8] = o;
        }
    }
}

// ================= GEMM1 (BK=64, R15 config): h16 = fp16( x @ w1h^T + b1 ), BN1 stats =========
__global__ __launch_bounds__(256, 2)
void gemm1_kernel(const float* __restrict__ x, const _Float16* __restrict__ w1h,
                  const float* __restrict__ b1, const float* __restrict__ zbuf,
                  _Float16* __restrict__ h16, float* __restrict__ sum1, float* __restrict__ ssq1)
{
    __shared__ __align__(16) _Float16 ldsA[2][8192];   // [buf][ks*4096 + row*32 + swz]
    __shared__ __align__(16) _Float16 ldsB[2][8192];   // [buf][ks*4096 + ch*512 + lane*8]
    __shared__ float redS[2][128], redQ[2][128];

    const int tid  = threadIdx.x;
    const int bid0 = blockIdx.x;
    const int vbid = (bid0 & 7) * 64 + (bid0 >> 3);    // XCD chunking (grid 512)
    const int bm = vbid >> 1, bn = vbid & 1;
    const int m0 = bm * 128, n0 = bn * 128;
    const int lane = tid & 63, wv = tid >> 6;
    const int wr = wv >> 1, wc = wv & 1;
    const int l15 = lane & 15, lg = lane >> 4;
    const int e3 = l15 & 3;
    const int nt = KPAD1 / 64;                          // 13

    const int r0g = tid >> 2, r1g = 64 + (tid >> 2), kq = tid & 3;
    const int wpos0 = r0g * 32 + ((kq ^ (r0g & 3)) * 8);
    const int wpos1 = r1g * 32 + ((kq ^ (r1g & 3)) * 8);
    const float* Ab0 = x + (size_t)(m0 + r0g) * IND + kq * 8;
    const float* Ab1 = x + (size_t)(m0 + r1g) * IND + kq * 8;

    const int brow = lane >> 2, bgp = (lane & 3) ^ (brow & 3);
    const _Float16* Bb = w1h + (size_t)(n0 + brow) * KPAD1 + bgp * 8;

    floatx4 acc[4][4];
    #pragma unroll
    for (int i = 0; i < 4; ++i)
        #pragma unroll
        for (int j = 0; j < 4; ++j) acc[i][j] = (floatx4){0.f, 0.f, 0.f, 0.f};

    floatx4 rgaE[8], rgaO[8];   // named reg sets (even/odd tiles)

    auto A_ISSUE = [&](floatx4 (&rg)[8], int t) {       // 8 global_load_dwordx4
        #pragma unroll
        for (int ks = 0; ks < 2; ++ks) {
            const int off = t * 64 + ks * 32;
            const bool v = (off + kq * 8) < IND;
            const float* p0 = v ? (Ab0 + off) : zbuf;
            const float* p1 = v ? (Ab1 + off) : zbuf;
            rg[ks*4+0] = *(const floatx4*)p0;
            rg[ks*4+1] = *(const floatx4*)(p0 + 4);
            rg[ks*4+2] = *(const floatx4*)p1;
            rg[ks*4+3] = *(const floatx4*)(p1 + 4);
        }
    };
    auto A_WRITE = [&](floatx4 (&rg)[8], int wb) {      // cvt + 4 ds_write_b128
        #pragma unroll
        for (int ks = 0; ks < 2; ++ks) {
            half8 h0, h1;
            #pragma unroll
            for (int j = 0; j < 4; ++j) {
                h0[j] = (_Float16)rg[ks*4+0][j]; h0[4+j] = (_Float16)rg[ks*4+1][j];
                h1[j] = (_Float16)rg[ks*4+2][j]; h1[4+j] = (_Float16)rg[ks*4+3][j];
            }
            *(half8*)&ldsA[wb][ks * 4096 + wpos0] = h0;
            *(half8*)&ldsA[wb][ks * 4096 + wpos1] = h1;
        }
    };
    auto B_ISSUE = [&](int bb, int t) {                 // 4 gld16
        const bool tok = t < nt;
        #pragma unroll
        for (int ks = 0; ks < 2; ++ks)
            #pragma unroll
            for (int c = 0; c < 2; ++c) {
                const int ch = wv + c * 4;
                const void* s = tok ? (const void*)(Bb + (size_t)ch * 16 * KPAD1 + t * 64 + ks * 32)
                                    : (const void*)zbuf;
                gld16(s, &ldsB[bb][ks * 4096 + ch * 512]);
            }
    };
    auto COMPUTE = [&](int abuf, int brd) {             // 2 ks-slices x 16 MFMA
        #pragma unroll
        for (int ks = 0; ks < 2; ++ks) {
            half8 af[4], bfr[4];
            #pragma unroll
            for (int i = 0; i < 4; ++i)
                af[i] = *(const half8*)&ldsA[abuf][ks*4096 + (wr*64 + i*16 + l15)*32 + ((lg ^ e3)*8)];
            #pragma unroll
            for (int j = 0; j < 4; ++j)
                bfr[j] = *(const half8*)&ldsB[brd][ks*4096 + (wc*4 + j)*512 + l15*32 + ((lg ^ e3)*8)];
            #pragma unroll
            for (int i = 0; i < 4; ++i)
                #pragma unroll
                for (int j = 0; j < 4; ++j)
                    acc[i][j] = __builtin_amdgcn_mfma_f32_16x16x32_f16(bfr[j], af[i], acc[i][j], 0, 0, 0);
        }
    };

    // ---- prologue ----
    A_ISSUE(rgaE, 0);
    B_ISSUE(0, 0);
    WAITVM(4);
    A_WRITE(rgaE, 0);
    A_ISSUE(rgaO, 1);
    WAITVM_BAR(8);

    // ---- main loop: 6 pairs (tiles 0..11) ----
    for (int p = 0; p < 6; ++p) {
        const int t = p * 2;
        B_ISSUE(1, t + 1);
        A_ISSUE(rgaE, t + 2);
        COMPUTE(0, 0);
        __builtin_amdgcn_sched_barrier(0);
        WAITVM(8);
        A_WRITE(rgaO, 1);
        WAITVM_BAR(8);
        B_ISSUE(0, t + 2);
        A_ISSUE(rgaO, t + 3);
        COMPUTE(1, 1);
        __builtin_amdgcn_sched_barrier(0);
        WAITVM(8);
        A_WRITE(rgaE, 0);
        WAITVM_BAR(8);
    }
    COMPUTE(0, 0);
    WAITVM(0);

    // ---- epilogue: bias, FP16 store, column stats from pre-rounded fp32 ----
    float sJ[4][4], qJ[4][4];
    #pragma unroll
    for (int j = 0; j < 4; ++j)
        #pragma unroll
        for (int r = 0; r < 4; ++r) { sJ[j][r] = 0.f; qJ[j][r] = 0.f; }
    #pragma unroll
    for (int i = 0; i < 4; ++i) {
        const int m = m0 + wr * 64 + i * 16 + l15;
        #pragma unroll
        for (int j = 0; j < 4; ++j) {
            const int nb = n0 + wc * 64 + j * 16 + lg * 4;
            float4 bt = *reinterpret_cast<const float4*>(&b1[nb]);
            float v[4] = {acc[i][j][0] + bt.x, acc[i][j][1] + bt.y,
                          acc[i][j][2] + bt.z, acc[i][j][3] + bt.w};
            half4v hv;
            hv[0] = (_Float16)v[0]; hv[1] = (_Float16)v[1];
            hv[2] = (_Float16)v[2]; hv[3] = (_Float16)v[3];
            *reinterpret_cast<half4v*>(&h16[(size_t)m * HIDD + nb]) = hv;
            #pragma unroll
            for (int r = 0; r < 4; ++r) { sJ[j][r] += v[r]; qJ[j][r] += v[r] * v[r]; }
        }
    }
    #pragma unroll
    for (int j = 0; j < 4; ++j)
        #pragma unroll
        for (int r = 0; r < 4; ++r) {
            float s = sJ[j][r], q = qJ[j][r];
            s += __shfl_xor(s, 1); s += __shfl_xor(s, 2);
            s += __shfl_xor(s, 4); s += __shfl_xor(s, 8);
            q += __shfl_xor(q, 1); q += __shfl_xor(q, 2);
            q += __shfl_xor(q, 4); q += __shfl_xor(q, 8);
            if (l15 == 0) {
                redS[wr][wc * 64 + j * 16 + lg * 4 + r] = s;
                redQ[wr][wc * 64 + j * 16 + lg * 4 + r] = q;
            }
        }
    __syncthreads();
    if (tid < 128) {
        atomicAdd(&sum1[n0 + tid], redS[0][tid] + redS[1][tid]);
        atomicAdd(&ssq1[n0 + tid], redQ[0][tid] + redQ[1][tid]);
    }
}

// ---------------- middle: BN1 finalize -> relu(bn1(h16)) -> log_map0 -> butterfly x3 ->
//                  exp_map0 -> ht16 (x65536) + BN2 raw stats.
//                  Fast transcendentals (v_log/v_exp), grid 1024 x 32 rows. ----------------
__global__ __launch_bounds__(256)
void mid_kernel(const _Float16* __restrict__ h16, const float* __restrict__ bfp,
                const float* __restrict__ sum1, const float* __restrict__ ssq1,
                const float* __restrict__ g1, const float* __restrict__ be1,
                _Float16* __restrict__ ht16, float* __restrict__ sum2, float* __restrict__ ssq2)
{
    __shared__ float s1sh[256], t1sh[256];
    __shared__ float bsum[4][256], bssq[4][256];
    const int tid  = threadIdx.x;
    {
        const float inv = 1.0f / (float)NBATCH;
        const float mu  = sum1[tid] * inv;
        const float var = fmaxf(ssq1[tid] * inv - mu * mu, 0.0f);
        const float rs  = 1.0f / sqrtf(var + 1e-5f);
        const float sj  = g1[tid] * rs;
        s1sh[tid] = sj;
        t1sh[tid] = fmaf(-mu, sj, be1[tid]);
    }
    __syncthreads();

    const int w    = tid >> 6;
    const int lane = tid & 63;
    const int row0 = blockIdx.x * 32 + w * 8;
    const int c0   = lane * 4;

    const float4 s1v = *reinterpret_cast<const float4*>(&s1sh[c0]);
    const float4 t1v = *reinterpret_cast<const float4*>(&t1sh[c0]);
    const float a0 = bfp[2 * lane],       a1 = bfp[2 * lane + 1];
    const float b0 = bfp[128 + 2 * lane], b1 = bfp[128 + 2 * lane + 1];
    const float a2 = bfp[256 + lane],     b2 = bfp[320 + lane];
    const float a3 = bfp[384 + (lane >> 1)], b3 = bfp[416 + (lane >> 1)];
    const float sgn = (lane & 1) ? -1.0f : 1.0f;
    const float sc  = sqrtf(1e-3f);

    float ps0 = 0, ps1 = 0, ps2 = 0, ps3 = 0;
    float q0 = 0, q1 = 0, q2 = 0, q3 = 0;

    for (int r = 0; r < 8; ++r) {
        const int row = row0 + r;
        half4v hv4 = *reinterpret_cast<const half4v*>(&h16[(size_t)row * HIDD + c0]);
        float x0 = fmaxf(fmaf((float)hv4[0], s1v.x, t1v.x), 0.0f);
        float x1 = fmaxf(fmaf((float)hv4[1], s1v.y, t1v.y), 0.0f);
        float x2 = fmaxf(fmaf((float)hv4[2], s1v.z, t1v.z), 0.0f);
        float x3 = fmaxf(fmaf((float)hv4[3], s1v.w, t1v.w), 0.0f);
        float n2 = x0 * x0 + x1 * x1 + x2 * x2 + x3 * x3;
        n2 = wave_allreduce_sum(n2);
        float sn = sc * sqrtf(n2);
        sn = fminf(fmaxf(sn, 1e-7f), 1.0f - 1e-6f);
        const float ls = fast_atanh(sn) * __frcp_rn(sn);
        x0 *= ls; x1 *= ls; x2 *= ls; x3 *= ls;
        const float y0 = fmaf(a0, x0,  b0 * x1);
        const float y1 = fmaf(a0, x1, -b0 * x0);
        const float y2 = fmaf(a1, x2,  b1 * x3);
        const float y3 = fmaf(a1, x3, -b1 * x2);
        const float z0 = fmaf(a2, y0,  b2 * y2);
        const float z1 = fmaf(a2, y1,  b2 * y3);
        const float z2 = fmaf(a2, y2, -b2 * y0);
        const float z3 = fmaf(a2, y3, -b2 * y1);
        const float p0 = __shfl_xor(z0, 1);
        const float p1 = __shfl_xor(z1, 1);
        const float p2 = __shfl_xor(z2, 1);
        const float p3 = __shfl_xor(z3, 1);
        const float w0 = fmaf(a3, z0, sgn * (b3 * p0));
        const float w1 = fmaf(a3, z1, sgn * (b3 * p1));
        const float w2 = fmaf(a3, z2, sgn * (b3 * p2));
        const float w3 = fmaf(a3, z3, sgn * (b3 * p3));
        float m2 = w0 * w0 + w1 * w1 + w2 * w2 + w3 * w3;
        m2 = wave_allreduce_sum(m2);
        const float sn2 = fmaxf(sc * sqrtf(m2), 1e-7f);
        const float es = fast_tanh(sn2) * __frcp_rn(sn2);
        const float o0 = es * w0, o1 = es * w1, o2 = es * w2, o3 = es * w3;
        half4v hv;
        hv[0] = (_Float16)(o0 * 65536.0f); hv[1] = (_Float16)(o1 * 65536.0f);
        hv[2] = (_Float16)(o2 * 65536.0f); hv[3] = (_Float16)(o3 * 65536.0f);
        *reinterpret_cast<half4v*>(&ht16[(size_t)row * HIDD + c0]) = hv;
        ps0 += o0; ps1 += o1; ps2 += o2; ps3 += o3;
        q0 += o0 * o0; q1 += o1 * o1; q2 += o2 * o2; q3 += o3 * o3;
    }

    bsum[w][c0 + 0] = ps0; bsum[w][c0 + 1] = ps1; bsum[w][c0 + 2] = ps2; bsum[w][c0 + 3] = ps3;
    bssq[w][c0 + 0] = q0;  bssq[w][c0 + 1] = q1;  bssq[w][c0 + 2] = q2;  bssq[w][c0 + 3] = q3;
    __syncthreads();
    if (tid < 256) {
        const float s = bsum[0][tid] + bsum[1][tid] + bsum[2][tid] + bsum[3][tid];
        const float q = bssq[0][tid] + bssq[1][tid] + bssq[2][tid] + bssq[3][tid];
        atomicAdd(&sum2[tid], s);
        atomicAdd(&ssq2[tid], q);
    }
}

// ================= GEMM2: out = relu(bn2(ht)) @ w2h^T + b2, BN2 fused at fragment read =========
__global__ __launch_bounds__(256, 3)
void gemm2_kernel(const _Float16* __restrict__ ht16, const _Float16* __restrict__ w2h,
                  const float* __restrict__ b2,
                  const float* __restrict__ sum2, const float* __restrict__ ssq2,
                  const float* __restrict__ g2, const float* __restrict__ be2,
                  const float* __restrict__ zbuf, float* __restrict__ out)
{
    __shared__ __align__(16) _Float16 ldsA[3][4096];   // 3 x 8KB
    __shared__ __align__(16) _Float16 ldsB[3][4096];
    __shared__ float sf[256], tf[256];

    const int tid = threadIdx.x;
    {
        const float inv = 1.0f / (float)NBATCH;
        const float mu  = sum2[tid] * inv;
        const float var = fmaxf(ssq2[tid] * inv - mu * mu, 0.0f);
        const float rs  = 1.0f / sqrtf(var + 1e-5f);
        const float sj  = g2[tid] * rs;
        sf[tid] = sj * (1024.0f / 65536.0f);
        tf[tid] = fmaf(-mu, sj, be2[tid]) * 1024.0f;
    }

    const int bid0 = blockIdx.x;
    const int vbid = (bid0 & 7) * 256 + (bid0 >> 3);   // XCD chunking (grid 2048)
    const int bm = vbid >> 3, bn = vbid & 7;
    const int m0 = bm * 128, n0 = bn * 128;
    const int lane = tid & 63, wv = tid >> 6;
    const int wr = wv >> 1, wc = wv & 1;
    const int l15 = lane & 15, lg = lane >> 4;
    const int e3 = l15 & 3;
    const int nt = HIDD / 32;                           // 8

    const int srow = lane >> 2, sgp = (lane & 3) ^ (srow & 3);
    const _Float16* Ab = ht16 + (size_t)(m0 + srow) * HIDD + sgp * 8;
    const _Float16* Bb = w2h  + (size_t)(n0 + srow) * HIDD + sgp * 8;

    floatx4 acc[4][4];
    #pragma unroll
    for (int i = 0; i < 4; ++i)
        #pragma unroll
        for (int j = 0; j < 4; ++j) acc[i][j] = (floatx4){0.f, 0.f, 0.f, 0.f};

    auto STAGE = [&](int buf, int t) {
        const int t32 = t * 32;
        const bool tok = t < nt;
        #pragma unroll
        for (int c = 0; c < 2; ++c) {
            const int ch = wv + c * 4;
            const void* sa = tok ? (const void*)(Ab + (size_t)ch * 16 * HIDD + t32)
                                 : (const void*)zbuf;
            const void* sb = tok ? (const void*)(Bb + (size_t)ch * 16 * HIDD + t32)
                                 : (const void*)zbuf;
            gld16(sa, &ldsA[buf][ch * 512]);
            gld16(sb, &ldsB[buf][ch * 512]);
        }
    };

    STAGE(0, 0);
    STAGE(1, 1);
    WAITVM_BAR(4);

    int buf = 0;
    for (int t = 0; t < nt; ++t) {
        int nbuf = buf + 2; if (nbuf >= 3) nbuf -= 3;
        STAGE(nbuf, t + 2);
        const int kb = t * 32 + lg * 8;
        float4 s0 = *(const float4*)&sf[kb], s1 = *(const float4*)&sf[kb + 4];
        float4 t0 = *(const float4*)&tf[kb], t1 = *(const float4*)&tf[kb + 4];
        half8 af[4], bfr[4];
        #pragma unroll
        for (int i = 0; i < 4; ++i) {
            half8 v = *(const half8*)&ldsA[buf][(wr * 4 + i) * 512 + l15 * 32 + ((lg ^ e3) * 8)];
            half8 hv;
            hv[0] = (_Float16)fmaxf(fmaf((float)v[0], s0.x, t0.x), 0.0f);
            hv[1] = (_Float16)fmaxf(fmaf((float)v[1], s0.y, t0.y), 0.0f);
            hv[2] = (_Float16)fmaxf(fmaf((float)v[2], s0.z, t0.z), 0.0f);
            hv[3] = (_Float16)fmaxf(fmaf((float)v[3], s0.w, t0.w), 0.0f);
            hv[4] = (_Float16)fmaxf(fmaf((float)v[4], s1.x, t1.x), 0.0f);
            hv[5] = (_Float16)fmaxf(fmaf((float)v[5], s1.y, t1.y), 0.0f);
            hv[6] = (_Float16)fmaxf(fmaf((float)v[6], s1.z, t1.z), 0.0f);
            hv[7] = (_Float16)fmaxf(fmaf((float)v[7], s1.w, t1.w), 0.0f);
            af[i] = hv;
        }
        #pragma unroll
        for (int j = 0; j < 4; ++j)
            bfr[j] = *(const half8*)&ldsB[buf][(wc * 4 + j) * 512 + l15 * 32 + ((lg ^ e3) * 8)];
        #pragma unroll
        for (int i = 0; i < 4; ++i)
            #pragma unroll
            for (int j = 0; j < 4; ++j)
                acc[i][j] = __builtin_amdgcn_mfma_f32_16x16x32_f16(bfr[j], af[i], acc[i][j], 0, 0, 0);
        WAITVM_BAR(4);
        buf = (buf + 1 == 3) ? 0 : buf + 1;
    }
    WAITVM(0);

    const float invScale = 1.0f / 1024.0f;
    #pragma unroll
    for (int i = 0; i < 4; ++i) {
        const int m = m0 + wr * 64 + i * 16 + l15;
        #pragma unroll
        for (int j = 0; j < 4; ++j) {
            const int nb = n0 + wc * 64 + j * 16 + lg * 4;
            float bj[4];
            if (nb + 4 <= OUTD) {
                float4 bt = *reinterpret_cast<const float4*>(&b2[nb]);
                bj[0] = bt.x; bj[1] = bt.y; bj[2] = bt.z; bj[3] = bt.w;
            } else {
                #pragma unroll
                for (int r = 0; r < 4; ++r) bj[r] = (nb + r < OUTD) ? b2[nb + r] : 0.0f;
            }
            float v[4];
            #pragma unroll
            for (int r = 0; r < 4; ++r) v[r] = fmaf(acc[i][j][r], invScale, bj[r]);
            if (nb + 4 <= OUTD) {
                *reinterpret_cast<float4*>(&out[(size_t)m * OUTD + nb]) =
                    make_float4(v[0], v[1], v[2], v[3]);
            } else {
                #pragma unroll
                for (int r = 0; r < 4; ++r)
                    if (nb + r < OUTD) out[(size_t)m * OUTD + nb + r] = v[r];
            }
        }
    }
}

extern "C" void kernel_launch(void* const* d_in, const int* in_sizes, int n_in,
                              void* d_out, int out_size, void* d_ws, size_t ws_size,
                              hipStream_t stream)
{
    const float* x   = (const float*)d_in[0];
    const float* w1  = (const float*)d_in[1];
    const float* b1  = (const float*)d_in[2];
    const float* g1  = (const float*)d_in[3];
    const float* be1 = (const float*)d_in[4];
    const float* bfp = (const float*)d_in[5];
    const float* g2  = (const float*)d_in[6];
    const float* be2 = (const float*)d_in[7];
    const float* w2  = (const float*)d_in[8];
    const float* b2  = (const float*)d_in[9];

    float* out = (float*)d_out;
    char*  wsb = (char*)d_ws;

    _Float16* ht16 = (_Float16*)(wsb);                    // 32768 x 256 fp16
    _Float16* w1h  = (_Float16*)(wsb + 16777216);         //   256 x 832 fp16
    _Float16* w2h  = (_Float16*)(wsb + 17203200);         //  1024 x 256 fp16
    float*    stat = (float*)  (wsb + 17727488);
    float* sum1 = stat;
    float* ssq1 = stat + 256;
    float* sum2 = stat + 512;
    float* ssq2 = stat + 768;
    float* zbuf = stat + 1024;

    _Float16* h16 = (_Float16*)out;   // parked in d_out; dead before gemm2 overwrites

    prep_kernel<<<232, 256, 0, stream>>>(w1, w1h, w2, w2h, stat);
    gemm1_kernel<<<512, 256, 0, stream>>>(x, w1h, b1, zbuf, h16, sum1, ssq1);
    mid_kernel<<<1024, 256, 0, stream>>>(h16, bfp, sum1, ssq1, g1, be1, ht16, sum2, ssq2);
    gemm2_kernel<<<2048, 256, 0, stream>>>(ht16, w2h, b2, sum2, ssq2, g2, be2, zbuf, out);
}